// Round 8
// baseline (34080.609 us; speedup 1.0000x reference)
//
#include <hip/hip_runtime.h>

typedef unsigned short ushort_t;
typedef __attribute__((ext_vector_type(8))) short short8;
typedef __attribute__((ext_vector_type(4))) float f32x4;
typedef __attribute__((ext_vector_type(4))) int i32x4;

#define NB   256     // batch
#define NT   512     // timesteps
#define ND   512     // input dim
#define NH   1024    // hidden dim
#define KK   1536    // NH + ND (fallback path concat K)
#define BK   128

// fast-path geometry: 4 groups x 64 rows; 64 slots/group; g = bid&3 so a
// group's blocks land on XCD pair {g, g+4} (perf heuristic only).
#define GROUPS      4
#define ROWS_PER_G  64
#define BLKS_PER_G  64
#define NBLK        256  // 1 block/CU, 512 threads

__device__ __forceinline__ ushort_t f2bf(float f) {
  union { float f; unsigned u; } v; v.f = f;
  unsigned u = v.u;
  return (ushort_t)((u + 0x7FFFu + ((u >> 16) & 1u)) >> 16);
}
__device__ __forceinline__ int pack2(float a, float b) {
  return (int)(((unsigned)f2bf(b) << 16) | (unsigned)f2bf(a));
}
__device__ __forceinline__ float bf2f(ushort_t h) {
  union { unsigned u; float f; } v; v.u = ((unsigned)h) << 16; return v.f;
}
__device__ __forceinline__ float sigmoidf_(float x) {
  return 1.f / (1.f + __expf(-x));
}
__device__ __forceinline__ float tanhf_(float x) {
  return 1.f - 2.f / (__expf(2.f * x) + 1.f);
}

// ===========================================================================
// Transpose-repack: src f32 [K][1024] -> dst bf16 [1024][K] (n-major).
// ===========================================================================
__global__ void repackT(const float* __restrict__ src, ushort_t* __restrict__ dst,
                        int K) {
  __shared__ float tile[64][65];
  const int k0 = blockIdx.x * 64, n0 = blockIdx.y * 64;
  const int tid = threadIdx.x;
  for (int i = 0; i < 16; ++i) {
    int e = tid + i * 256;
    int r = e >> 6, c = e & 63;
    tile[r][c] = src[(size_t)(k0 + r) * 1024 + n0 + c];
  }
  __syncthreads();
  for (int i = 0; i < 2; ++i) {
    int cch = tid + i * 256;
    int nl = cch >> 3, kc = (cch & 7) * 8;
    ushort_t tmp[8];
#pragma unroll
    for (int j = 0; j < 8; ++j) tmp[j] = f2bf(tile[kc + j][nl]);
    *reinterpret_cast<i32x4*>(dst + (size_t)(n0 + nl) * K + k0 + kc) =
        *reinterpret_cast<i32x4*>(tmp);
  }
}

__global__ void init_fast(ushort_t* __restrict__ hb, float* __restrict__ hf,
                          unsigned* __restrict__ flags) {
  int i = blockIdx.x * 256 + threadIdx.x;
  if (i < NB * NH) { hb[i] = 0; hf[i] = 0.f; }
  if (i < GROUPS * BLKS_PER_G) flags[i] = 0u;
}

// ===========================================================================
// Gx precompute (verified rounds 6/7): Gx[t*256+b][j], j: 0..1023=z,
// 1024..2047=r, 2048..3071=cand. Bx bf16 [3072][512] n-major.
// ===========================================================================
__global__ void __launch_bounds__(256)
gxgemm(const float* __restrict__ x, const ushort_t* __restrict__ Bx,
       const float* __restrict__ bz, const float* __restrict__ br,
       const float* __restrict__ bb, ushort_t* __restrict__ Gx) {
  __shared__ __align__(16) char smem[32768];
  const int tid  = threadIdx.x;
  const int m0   = blockIdx.x * 64;
  const int n0   = blockIdx.y * 64;
  const int lane = tid & 63;
  const int w    = tid >> 6;
  const int wm   = w >> 1, wn = w & 1;
  const int l15  = lane & 15, l4 = lane >> 4;

  f32x4 acc[2][2];
#pragma unroll
  for (int i = 0; i < 2; ++i)
#pragma unroll
    for (int j = 0; j < 2; ++j) acc[i][j] = (f32x4){0.f, 0.f, 0.f, 0.f};

  for (int kb = 0; kb < 4; ++kb) {
    const int kbase = kb * BK;
#pragma unroll
    for (int i = 0; i < 4; ++i) {
      int c = tid + (i << 8);
      int r = c >> 4, kc = (c & 15) << 3;
      int m = m0 + r;
      int tt = m >> 8, b = m & 255;
      const float* xp = x + ((size_t)b * NT + tt) * ND + kbase + kc;
      f32x4 f0 = *reinterpret_cast<const f32x4*>(xp);
      f32x4 f1 = *reinterpret_cast<const f32x4*>(xp + 4);
      i32x4 v;
      v[0] = pack2(f0[0], f0[1]); v[1] = pack2(f0[2], f0[3]);
      v[2] = pack2(f1[0], f1[1]); v[3] = pack2(f1[2], f1[3]);
      int off = (r << 8) + (((kc << 1)) ^ ((r & 7) << 4));
      *reinterpret_cast<i32x4*>(&smem[off]) = v;
    }
#pragma unroll
    for (int i = 0; i < 4; ++i) {
      int c = tid + (i << 8);
      int n = c >> 4, kc = (c & 15) << 3;
      i32x4 v = *reinterpret_cast<const i32x4*>(Bx + (size_t)(n0 + n) * 512 + kbase + kc);
      int off = 16384 + (n << 8) + (((kc << 1)) ^ ((n & 7) << 4));
      *reinterpret_cast<i32x4*>(&smem[off]) = v;
    }
    __syncthreads();
#pragma unroll
    for (int ks = 0; ks < 4; ++ks) {
      int kbyte = ks * 64 + l4 * 16;
      short8 a[2], b[2];
#pragma unroll
      for (int i = 0; i < 2; ++i) {
        int ra = wm * 32 + i * 16 + l15;
        a[i] = *reinterpret_cast<short8*>(&smem[(ra << 8) + (kbyte ^ ((ra & 7) << 4))]);
        int nb = wn * 32 + i * 16 + l15;
        b[i] = *reinterpret_cast<short8*>(&smem[16384 + (nb << 8) + (kbyte ^ ((nb & 7) << 4))]);
      }
#pragma unroll
      for (int i = 0; i < 2; ++i)
#pragma unroll
        for (int j = 0; j < 2; ++j)
          acc[i][j] = __builtin_amdgcn_mfma_f32_16x16x32_bf16(a[i], b[j], acc[i][j], 0, 0, 0);
    }
    __syncthreads();
  }
#pragma unroll
  for (int i = 0; i < 2; ++i)
#pragma unroll
    for (int j = 0; j < 2; ++j) {
      int col = n0 + wn * 32 + j * 16 + l15;
      float bias = (col < NH) ? bz[col] : (col < 2 * NH ? br[col - NH] : bb[col - 2 * NH]);
      int mr = m0 + wm * 32 + i * 16 + 4 * l4;
#pragma unroll
      for (int jj = 0; jj < 4; ++jj)
        Gx[(size_t)(mr + jj) * 3072 + col] = f2bf(acc[i][j][jj] + bias);
    }
}

// ---------------------------------------------------------------------------
// Group barrier (proven rounds 4-7): 64-slot flag array, agent scope.
// ---------------------------------------------------------------------------
__device__ __forceinline__ void group_barrier(unsigned* flags, int g, int slot,
                                              unsigned target, int tid) {
  __syncthreads();
  if (tid == 0) {
    __hip_atomic_store(flags + g * BLKS_PER_G + slot, target,
                       __ATOMIC_RELEASE, __HIP_MEMORY_SCOPE_AGENT);
  }
  if (tid < BLKS_PER_G) {
    while (__hip_atomic_load(flags + g * BLKS_PER_G + tid,
                             __ATOMIC_RELAXED, __HIP_MEMORY_SCOPE_AGENT) < target) {
      __builtin_amdgcn_s_sleep(2);
    }
  }
  __syncthreads();
  __builtin_amdgcn_fence(__ATOMIC_ACQUIRE, "agent");
}

// ===========================================================================
// Persistent GRU v5: XCD-pair groups + ALL weights LDS-stationary.
// 256 blocks x 512 threads (1 block/CU, 8 waves). g=bid&3, slot=bid>>2.
// LDS 96KB: B1 (32 cols x 1024 K, 64KB) + B2 (16 cols x 1024 K, 32KB),
// chunked layout [kc8][col][16B] -> conflict-free ds_read_b128.
// phase1: 8 waves, tile (mt=w>>1, ct=w&1): rows rowbase+16mt.., cols
//         slot*32+16ct.., full K=1024 -> 32 MFMA, acc = 4 VGPRs.
// phase2: waves 0..3: rows rowbase+16w.., cols slot*16.., full K.
// ===========================================================================
__global__ void __launch_bounds__(512, 1)
gru_v5(const ushort_t* __restrict__ Gx,
       const ushort_t* __restrict__ Bu1, const ushort_t* __restrict__ Bu2,
       ushort_t* __restrict__ hb, ushort_t* __restrict__ rhb,
       float* __restrict__ hf, float* __restrict__ zfb,
       unsigned* __restrict__ flags, float* __restrict__ out) {
  extern __shared__ __align__(16) char dsm[];   // 98304 B: B1 64KB | B2 32KB

  const int tid  = threadIdx.x;
  const int bid  = blockIdx.x;
  const int w    = tid >> 6;
  const int lane = tid & 63;
  const int l15  = lane & 15;
  const int l4   = lane >> 4;
  const int g    = bid & 3;
  const int slot = bid >> 2;
  const int n1g  = slot * 32;            // phase1 col base (0..2047)
  const int n2g  = slot * 16;            // phase2 col base (0..1023)
  const int rowbase = g * ROWS_PER_G;

  // ---- preload weight slices into LDS (chunked [kc8][col][16B]) ----
#pragma unroll
  for (int i = 0; i < 8; ++i) {          // B1: 4096 chunks
    int c = tid + i * 512;
    int kc8 = c >> 5, col = c & 31;
    i32x4 v = *reinterpret_cast<const i32x4*>(
        Bu1 + (size_t)(n1g + col) * NH + kc8 * 8);
    *reinterpret_cast<i32x4*>(&dsm[kc8 * 512 + col * 16]) = v;
  }
#pragma unroll
  for (int i = 0; i < 4; ++i) {          // B2: 2048 chunks
    int c = tid + i * 512;
    int kc8 = c >> 4, col = c & 15;
    i32x4 v = *reinterpret_cast<const i32x4*>(
        Bu2 + (size_t)(n2g + col) * NH + kc8 * 8);
    *reinterpret_cast<i32x4*>(&dsm[65536 + kc8 * 256 + col * 16]) = v;
  }
  __syncthreads();

  // ---- per-thread coordinates ----
  const int mt1 = w >> 1, ct1 = w & 1;
  const int col1 = n1g + ct1 * 16 + l15;
  const int r0_1 = rowbase + 16 * mt1 + 4 * l4;
  const bool zside = (slot < 32);
  const ushort_t* arow1 = hb + (size_t)(rowbase + 16 * mt1 + l15) * NH;
  const int b1base = ct1 * 256 + l15 * 16;

  const int col2 = n2g + l15;                       // phase2 (waves 0..3)
  const int r0_2 = rowbase + 16 * w + 4 * l4;
  const ushort_t* arow2 = rhb + (size_t)(rowbase + 16 * w + l15) * NH;
  const int b2base = 65536 + l15 * 16;

  unsigned epoch = 0;

  for (int t = 0; t < NT; ++t) {
    const size_t gxbase = (size_t)t * NB * 3072;

    // ================= phase 1: z | r =================
    float gx1[4], hfpre[4];
#pragma unroll
    for (int jj = 0; jj < 4; ++jj)
      gx1[jj] = bf2f(Gx[gxbase + (size_t)(r0_1 + jj) * 3072 + col1]);
    if (!zside) {
      int cc = col1 - NH;
#pragma unroll
      for (int jj = 0; jj < 4; ++jj)
        hfpre[jj] = hf[(size_t)(r0_1 + jj) * NH + cc];
    }

    f32x4 acc = {0.f, 0.f, 0.f, 0.f};
#pragma unroll
    for (int s = 0; s < 32; ++s) {
      short8 a = *reinterpret_cast<const short8*>(arow1 + 32 * s + 8 * l4);
      short8 b = *reinterpret_cast<const short8*>(
          &dsm[b1base + (4 * s + l4) * 512]);
      acc = __builtin_amdgcn_mfma_f32_16x16x32_bf16(a, b, acc, 0, 0, 0);
    }
    if (zside) {
#pragma unroll
      for (int jj = 0; jj < 4; ++jj)
        zfb[(size_t)(r0_1 + jj) * NH + col1] = sigmoidf_(acc[jj] + gx1[jj]);
    } else {
      int cc = col1 - NH;
#pragma unroll
      for (int jj = 0; jj < 4; ++jj) {
        float rv = sigmoidf_(acc[jj] + gx1[jj]);
        rhb[(size_t)(r0_1 + jj) * NH + cc] = f2bf(rv * hfpre[jj]);
      }
    }

    // prefetch phase2 operands independent of phase1 (hide under barrier)
    float gxc[4], hf2[4];
    if (w < 4) {
#pragma unroll
      for (int jj = 0; jj < 4; ++jj) {
        gxc[jj] = bf2f(Gx[gxbase + (size_t)(r0_2 + jj) * 3072 + 2048 + col2]);
        hf2[jj] = hf[(size_t)(r0_2 + jj) * NH + col2];
      }
    }

    ++epoch;
    group_barrier(flags, g, slot, epoch, tid);

    // ================= phase 2: h_cand + update =================
    if (w < 4) {
      float zpre[4];
#pragma unroll
      for (int jj = 0; jj < 4; ++jj)
        zpre[jj] = zfb[(size_t)(r0_2 + jj) * NH + col2];

      f32x4 acc2 = {0.f, 0.f, 0.f, 0.f};
#pragma unroll
      for (int s = 0; s < 32; ++s) {
        short8 a = *reinterpret_cast<const short8*>(arow2 + 32 * s + 8 * l4);
        short8 b = *reinterpret_cast<const short8*>(
            &dsm[b2base + (4 * s + l4) * 256]);
        acc2 = __builtin_amdgcn_mfma_f32_16x16x32_bf16(a, b, acc2, 0, 0, 0);
      }
#pragma unroll
      for (int jj = 0; jj < 4; ++jj) {
        size_t idx = (size_t)(r0_2 + jj) * NH + col2;
        float hc = tanhf_(acc2[jj] + gxc[jj]);
        float zv = zpre[jj];
        float hn = (1.f - zv) * hf2[jj] + zv * hc;
        hf[idx] = hn;
        hb[idx] = f2bf(hn);
        if (t == NT - 1) out[idx] = hn;
      }
    }
    ++epoch;
    group_barrier(flags, g, slot, epoch, tid);
  }
}

// ===========================================================================
// ============== FALLBACK (round-2, proven): per-step launches ==============
// ===========================================================================
__global__ void repack_weights(const float* __restrict__ U,  const float* __restrict__ W,
                               const float* __restrict__ Uz, const float* __restrict__ Wz,
                               const float* __restrict__ Ur, const float* __restrict__ Wr,
                               ushort_t* __restrict__ B1t, ushort_t* __restrict__ B2t) {
  const int kt = blockIdx.x, nt = blockIdx.y, which = blockIdx.z;
  if (which == 1 && nt >= 16) return;
  __shared__ float tile[64][65];
  const int k0 = kt * 64, n0 = nt * 64;
  const int tid = threadIdx.x;
  for (int i = 0; i < 16; ++i) {
    int e = tid + i * 256;
    int r = e >> 6, c = e & 63;
    int k = k0 + r, n = n0 + c;
    int nn = n & 1023;
    const float* src;
    if (which == 0) {
      if (k < NH) src = (n < NH ? Uz : Ur) + (size_t)k * NH + nn;
      else        src = (n < NH ? Wz : Wr) + (size_t)(k - NH) * NH + nn;
    } else {
      if (k < NH) src = U + (size_t)k * NH + nn;
      else        src = W + (size_t)(k - NH) * NH + nn;
    }
    tile[r][c] = *src;
  }
  __syncthreads();
  ushort_t* dst = (which == 0) ? B1t : B2t;
  for (int i = 0; i < 2; ++i) {
    int cch = tid + i * 256;
    int nl = cch >> 3, kc = (cch & 7) * 8;
    ushort_t tmp[8];
#pragma unroll
    for (int j = 0; j < 8; ++j) tmp[j] = f2bf(tile[kc + j][nl]);
    *reinterpret_cast<i32x4*>(dst + (size_t)(n0 + nl) * KK + k0 + kc) =
        *reinterpret_cast<i32x4*>(tmp);
  }
}

__global__ void init_state(ushort_t* __restrict__ hb, float* __restrict__ hf) {
  int i = blockIdx.x * 256 + threadIdx.x;
  if (i < NB * NH) { hb[i] = 0; hf[i] = 0.f; }
}

__global__ void __launch_bounds__(256)
gru_phase1(const float* __restrict__ x, const ushort_t* __restrict__ B1t,
           const ushort_t* __restrict__ hb, ushort_t* __restrict__ rhb,
           const float* __restrict__ hf, float* __restrict__ zfb,
           const float* __restrict__ bz, const float* __restrict__ br, int t) {
  __shared__ __align__(16) char smem[24576];
  const int tid  = threadIdx.x;
  const int bid  = blockIdx.x;
  const int lane = tid & 63;
  const int w    = tid >> 6;
  const int wm   = w >> 1, wn = w & 1;
  const int m0   = (bid >> 5) * 32;
  const int n1   = (bid & 31) * 64;
  const int l15  = lane & 15, l4 = lane >> 4;

  f32x4 acc0 = {0.f, 0.f, 0.f, 0.f}, acc1 = {0.f, 0.f, 0.f, 0.f};
  for (int kb = 0; kb < KK / BK; ++kb) {
    const int kbase = kb * BK;
#pragma unroll
    for (int i = 0; i < 2; ++i) {
      int c = tid + (i << 8);
      int r = c >> 4, kc = (c & 15) << 3;
      int m = m0 + r, k = kbase + kc;
      i32x4 v;
      if (k < NH) {
        v = *reinterpret_cast<const i32x4*>(hb + (size_t)m * NH + k);
      } else {
        const float* xp = x + (size_t)m * (NT * ND) + (size_t)t * ND + (k - NH);
        f32x4 f0 = *reinterpret_cast<const f32x4*>(xp);
        f32x4 f1 = *reinterpret_cast<const f32x4*>(xp + 4);
        v[0] = pack2(f0[0], f0[1]); v[1] = pack2(f0[2], f0[3]);
        v[2] = pack2(f1[0], f1[1]); v[3] = pack2(f1[2], f1[3]);
      }
      int off = (r << 8) + (((kc << 1)) ^ ((r & 7) << 4));
      *reinterpret_cast<i32x4*>(&smem[off]) = v;
    }
#pragma unroll
    for (int i = 0; i < 4; ++i) {
      int c = tid + (i << 8);
      int n = c >> 4, kc = (c & 15) << 3;
      i32x4 v = *reinterpret_cast<const i32x4*>(B1t + (size_t)(n1 + n) * KK + kbase + kc);
      int off = 8192 + (n << 8) + (((kc << 1)) ^ ((n & 7) << 4));
      *reinterpret_cast<i32x4*>(&smem[off]) = v;
    }
    __syncthreads();
#pragma unroll
    for (int ks = 0; ks < 4; ++ks) {
      int kbyte = ks * 64 + l4 * 16;
      int ra = wm * 16 + l15;
      short8 a = *reinterpret_cast<short8*>(&smem[(ra << 8) + (kbyte ^ ((ra & 7) << 4))]);
      int nb0 = wn * 32 + l15;
      short8 b0 = *reinterpret_cast<short8*>(&smem[8192 + (nb0 << 8) + (kbyte ^ ((nb0 & 7) << 4))]);
      int nb1 = nb0 + 16;
      short8 b1 = *reinterpret_cast<short8*>(&smem[8192 + (nb1 << 8) + (kbyte ^ ((nb1 & 7) << 4))]);
      acc0 = __builtin_amdgcn_mfma_f32_16x16x32_bf16(a, b0, acc0, 0, 0, 0);
      acc1 = __builtin_amdgcn_mfma_f32_16x16x32_bf16(a, b1, acc1, 0, 0, 0);
    }
    __syncthreads();
  }
  int mrow = m0 + wm * 16 + l4 * 4;
#pragma unroll
  for (int f = 0; f < 2; ++f) {
    f32x4 av = f ? acc1 : acc0;
    int c = n1 + wn * 32 + f * 16 + l15;
#pragma unroll
    for (int j = 0; j < 4; ++j) {
      int m = mrow + j;
      float v = av[j];
      if (c < NH) {
        zfb[(size_t)m * NH + c] = sigmoidf_(v + bz[c]);
      } else {
        int cc = c - NH;
        float rv = sigmoidf_(v + br[cc]);
        rhb[(size_t)m * NH + cc] = f2bf(rv * hf[(size_t)m * NH + cc]);
      }
    }
  }
}

__global__ void __launch_bounds__(256)
gru_phase2(const float* __restrict__ x, const ushort_t* __restrict__ B2t,
           ushort_t* __restrict__ hb, const ushort_t* __restrict__ rhb,
           float* __restrict__ hf, const float* __restrict__ zfb,
           const float* __restrict__ bb, float* __restrict__ out, int t) {
  __shared__ __align__(16) char smem[16384];
  const int tid  = threadIdx.x;
  const int bid  = blockIdx.x;
  const int lane = tid & 63;
  const int w    = tid >> 6;
  const int wm   = w >> 1, wn = w & 1;
  const int m0   = (bid >> 5) * 32;
  const int n2   = (bid & 31) * 32;
  const int l15  = lane & 15, l4 = lane >> 4;

  f32x4 acc = {0.f, 0.f, 0.f, 0.f};
  for (int kb = 0; kb < KK / BK; ++kb) {
    const int kbase = kb * BK;
#pragma unroll
    for (int i = 0; i < 2; ++i) {
      int c = tid + (i << 8);
      int r = c >> 4, kc = (c & 15) << 3;
      int m = m0 + r, k = kbase + kc;
      i32x4 v;
      if (k < NH) {
        v = *reinterpret_cast<const i32x4*>(rhb + (size_t)m * NH + k);
      } else {
        const float* xp = x + (size_t)m * (NT * ND) + (size_t)t * ND + (k - NH);
        f32x4 f0 = *reinterpret_cast<const f32x4*>(xp);
        f32x4 f1 = *reinterpret_cast<const f32x4*>(xp + 4);
        v[0] = pack2(f0[0], f0[1]); v[1] = pack2(f0[2], f0[3]);
        v[2] = pack2(f1[0], f1[1]); v[3] = pack2(f1[2], f1[3]);
      }
      int off = (r << 8) + (((kc << 1)) ^ ((r & 7) << 4));
      *reinterpret_cast<i32x4*>(&smem[off]) = v;
    }
#pragma unroll
    for (int i = 0; i < 2; ++i) {
      int c = tid + (i << 8);
      int n = c >> 4, kc = (c & 15) << 3;
      i32x4 v = *reinterpret_cast<const i32x4*>(B2t + (size_t)(n2 + n) * KK + kbase + kc);
      int off = 8192 + (n << 8) + (((kc << 1)) ^ ((n & 7) << 4));
      *reinterpret_cast<i32x4*>(&smem[off]) = v;
    }
    __syncthreads();
#pragma unroll
    for (int ks = 0; ks < 4; ++ks) {
      int kbyte = ks * 64 + l4 * 16;
      int ra = wm * 16 + l15;
      short8 a = *reinterpret_cast<short8*>(&smem[(ra << 8) + (kbyte ^ ((ra & 7) << 4))]);
      int nb = wn * 16 + l15;
      short8 b0 = *reinterpret_cast<short8*>(&smem[8192 + (nb << 8) + (kbyte ^ ((nb & 7) << 4))]);
      acc = __builtin_amdgcn_mfma_f32_16x16x32_bf16(a, b0, acc, 0, 0, 0);
    }
    __syncthreads();
  }
  int mrow = m0 + wm * 16 + l4 * 4;
  int c = n2 + wn * 16 + l15;
#pragma unroll
  for (int j = 0; j < 4; ++j) {
    int m = mrow + j;
    size_t idx = (size_t)m * NH + c;
    float hc = tanhf_(acc[j] + bb[c]);
    float zv = zfb[idx];
    float hn = (1.f - zv) * hf[idx] + zv * hc;
    hf[idx] = hn;
    hb[idx] = f2bf(hn);
    if (t == NT - 1) out[idx] = hn;
  }
}

// ===========================================================================
extern "C" void kernel_launch(void* const* d_in, const int* in_sizes, int n_in,
                              void* d_out, int out_size, void* d_ws, size_t ws_size,
                              hipStream_t stream) {
  const float* x  = (const float*)d_in[0];
  const float* W  = (const float*)d_in[1];
  const float* U  = (const float*)d_in[2];
  const float* Wz = (const float*)d_in[3];
  const float* Uz = (const float*)d_in[4];
  const float* Wr = (const float*)d_in[5];
  const float* Ur = (const float*)d_in[6];
  const float* bb = (const float*)d_in[7];
  const float* bz = (const float*)d_in[8];
  const float* br = (const float*)d_in[9];
  float* out = (float*)d_out;
  char* ws = (char*)d_ws;

  // fast-path workspace layout
  ushort_t* Bu1   = (ushort_t*)(ws);                  //  4,194,304
  ushort_t* Bu2   = (ushort_t*)(ws + 4194304);        //  2,097,152
  ushort_t* Bx    = (ushort_t*)(ws + 6291456);        //  3,145,728
  ushort_t* hb    = (ushort_t*)(ws + 9437184);        //    524,288
  ushort_t* rhb   = (ushort_t*)(ws + 9961472);        //    524,288
  float*    hf    = (float*)   (ws + 10485760);       //  1,048,576
  float*    zfb   = (float*)   (ws + 11534336);       //  1,048,576
  unsigned* flags = (unsigned*)(ws + 12582912);       //      4,096
  ushort_t* Gx    = (ushort_t*)(ws + 12587008);       // 805,306,368 -> 817,893,376

  const bool fast = (ws_size >= (size_t)817893376ULL);

  if (fast) {
    (void)hipFuncSetAttribute(reinterpret_cast<const void*>(&gru_v5),
                              hipFuncAttributeMaxDynamicSharedMemorySize, 98304);
    hipLaunchKernelGGL(repackT, dim3(16, 16), dim3(256), 0, stream, Uz, Bu1, NH);
    hipLaunchKernelGGL(repackT, dim3(16, 16), dim3(256), 0, stream, Ur, Bu1 + (size_t)NH * NH, NH);
    hipLaunchKernelGGL(repackT, dim3(16, 16), dim3(256), 0, stream, U,  Bu2, NH);
    hipLaunchKernelGGL(repackT, dim3(8, 16),  dim3(256), 0, stream, Wz, Bx, ND);
    hipLaunchKernelGGL(repackT, dim3(8, 16),  dim3(256), 0, stream, Wr, Bx + (size_t)NH * ND, ND);
    hipLaunchKernelGGL(repackT, dim3(8, 16),  dim3(256), 0, stream, W,  Bx + (size_t)2 * NH * ND, ND);
    hipLaunchKernelGGL(init_fast, dim3(1024), dim3(256), 0, stream, hb, hf, flags);
    hipLaunchKernelGGL(gxgemm, dim3(2048, 48), dim3(256), 0, stream, x, Bx, bz, br, bb, Gx);
    hipLaunchKernelGGL(gru_v5, dim3(NBLK), dim3(512), 98304, stream,
                       Gx, Bu1, Bu2, hb, rhb, hf, zfb, flags, out);
  } else {
    // fallback: proven round-2 per-step path
    ushort_t* B1t  = (ushort_t*)(ws);
    ushort_t* B2t  = (ushort_t*)(ws + 6291456);
    ushort_t* hb2  = (ushort_t*)(ws + 9437184);
    ushort_t* rhb2 = (ushort_t*)(ws + 9961472);
    float*    hf2  = (float*)   (ws + 10485760);
    float*    zfb2 = (float*)   (ws + 11534336);
    hipLaunchKernelGGL(repack_weights, dim3(24, 32, 2), dim3(256), 0, stream,
                       U, W, Uz, Wz, Ur, Wr, B1t, B2t);
    hipLaunchKernelGGL(init_state, dim3(1024), dim3(256), 0, stream, hb2, hf2);
    for (int t = 0; t < NT; ++t) {
      hipLaunchKernelGGL(gru_phase1, dim3(256), dim3(256), 0, stream,
                         x, B1t, hb2, rhb2, hf2, zfb2, bz, br, t);
      hipLaunchKernelGGL(gru_phase2, dim3(256), dim3(256), 0, stream,
                         x, B2t, hb2, rhb2, hf2, zfb2, bb, out, t);
    }
  }
}

// Round 9
// 12150.977 us; speedup vs baseline: 2.8048x; 2.8048x over previous
//
#include <hip/hip_runtime.h>

typedef unsigned short ushort_t;
typedef __attribute__((ext_vector_type(8))) short short8;
typedef __attribute__((ext_vector_type(4))) float f32x4;
typedef __attribute__((ext_vector_type(4))) int i32x4;

#define NB   256     // batch
#define NT   512     // timesteps
#define ND   512     // input dim
#define NH   1024    // hidden dim
#define KK   1536    // NH + ND (fallback path concat K)
#define BK   128

__device__ __forceinline__ ushort_t f2bf(float f) {
  union { float f; unsigned u; } v; v.f = f;
  unsigned u = v.u;
  return (ushort_t)((u + 0x7FFFu + ((u >> 16) & 1u)) >> 16);
}
__device__ __forceinline__ int pack2(float a, float b) {
  return (int)(((unsigned)f2bf(b) << 16) | (unsigned)f2bf(a));
}
__device__ __forceinline__ float bf2f(ushort_t h) {
  union { unsigned u; float f; } v; v.u = ((unsigned)h) << 16; return v.f;
}
__device__ __forceinline__ float sigmoidf_(float x) {
  return 1.f / (1.f + __expf(-x));
}
__device__ __forceinline__ float tanhf_(float x) {
  return 1.f - 2.f / (__expf(2.f * x) + 1.f);
}

// ===========================================================================
// Transpose-repack (verified r6-r8): src f32 [K][1024] -> dst bf16 [1024][K].
// ===========================================================================
__global__ void repackT(const float* __restrict__ src, ushort_t* __restrict__ dst,
                        int K) {
  __shared__ float tile[64][65];
  const int k0 = blockIdx.x * 64, n0 = blockIdx.y * 64;
  const int tid = threadIdx.x;
  for (int i = 0; i < 16; ++i) {
    int e = tid + i * 256;
    int r = e >> 6, c = e & 63;
    tile[r][c] = src[(size_t)(k0 + r) * 1024 + n0 + c];
  }
  __syncthreads();
  for (int i = 0; i < 2; ++i) {
    int cch = tid + i * 256;
    int nl = cch >> 3, kc = (cch & 7) * 8;
    ushort_t tmp[8];
#pragma unroll
    for (int j = 0; j < 8; ++j) tmp[j] = f2bf(tile[kc + j][nl]);
    *reinterpret_cast<i32x4*>(dst + (size_t)(n0 + nl) * K + k0 + kc) =
        *reinterpret_cast<i32x4*>(tmp);
  }
}

__global__ void init_state(ushort_t* __restrict__ hb, float* __restrict__ hf) {
  int i = blockIdx.x * 256 + threadIdx.x;
  if (i < NB * NH) { hb[i] = 0; hf[i] = 0.f; }
}

// ===========================================================================
// Gx precompute (verified r6-r8): Gx[t*256+b][j], j: 0..1023=z, 1024..2047=r,
// 2048..3071=cand. Bx bf16 [3072][512] n-major.
// ===========================================================================
__global__ void __launch_bounds__(256)
gxgemm(const float* __restrict__ x, const ushort_t* __restrict__ Bx,
       const float* __restrict__ bz, const float* __restrict__ br,
       const float* __restrict__ bb, ushort_t* __restrict__ Gx) {
  __shared__ __align__(16) char smem[32768];
  const int tid  = threadIdx.x;
  const int m0   = blockIdx.x * 64;
  const int n0   = blockIdx.y * 64;
  const int lane = tid & 63;
  const int w    = tid >> 6;
  const int wm   = w >> 1, wn = w & 1;
  const int l15  = lane & 15, l4 = lane >> 4;

  f32x4 acc[2][2];
#pragma unroll
  for (int i = 0; i < 2; ++i)
#pragma unroll
    for (int j = 0; j < 2; ++j) acc[i][j] = (f32x4){0.f, 0.f, 0.f, 0.f};

  for (int kb = 0; kb < 4; ++kb) {
    const int kbase = kb * BK;
#pragma unroll
    for (int i = 0; i < 4; ++i) {
      int c = tid + (i << 8);
      int r = c >> 4, kc = (c & 15) << 3;
      int m = m0 + r;
      int tt = m >> 8, b = m & 255;
      const float* xp = x + ((size_t)b * NT + tt) * ND + kbase + kc;
      f32x4 f0 = *reinterpret_cast<const f32x4*>(xp);
      f32x4 f1 = *reinterpret_cast<const f32x4*>(xp + 4);
      i32x4 v;
      v[0] = pack2(f0[0], f0[1]); v[1] = pack2(f0[2], f0[3]);
      v[2] = pack2(f1[0], f1[1]); v[3] = pack2(f1[2], f1[3]);
      int off = (r << 8) + (((kc << 1)) ^ ((r & 7) << 4));
      *reinterpret_cast<i32x4*>(&smem[off]) = v;
    }
#pragma unroll
    for (int i = 0; i < 4; ++i) {
      int c = tid + (i << 8);
      int n = c >> 4, kc = (c & 15) << 3;
      i32x4 v = *reinterpret_cast<const i32x4*>(Bx + (size_t)(n0 + n) * 512 + kbase + kc);
      int off = 16384 + (n << 8) + (((kc << 1)) ^ ((n & 7) << 4));
      *reinterpret_cast<i32x4*>(&smem[off]) = v;
    }
    __syncthreads();
#pragma unroll
    for (int ks = 0; ks < 4; ++ks) {
      int kbyte = ks * 64 + l4 * 16;
      short8 a[2], b[2];
#pragma unroll
      for (int i = 0; i < 2; ++i) {
        int ra = wm * 32 + i * 16 + l15;
        a[i] = *reinterpret_cast<short8*>(&smem[(ra << 8) + (kbyte ^ ((ra & 7) << 4))]);
        int nb = wn * 32 + i * 16 + l15;
        b[i] = *reinterpret_cast<short8*>(&smem[16384 + (nb << 8) + (kbyte ^ ((nb & 7) << 4))]);
      }
#pragma unroll
      for (int i = 0; i < 2; ++i)
#pragma unroll
        for (int j = 0; j < 2; ++j)
          acc[i][j] = __builtin_amdgcn_mfma_f32_16x16x32_bf16(a[i], b[j], acc[i][j], 0, 0, 0);
    }
    __syncthreads();
  }
#pragma unroll
  for (int i = 0; i < 2; ++i)
#pragma unroll
    for (int j = 0; j < 2; ++j) {
      int col = n0 + wn * 32 + j * 16 + l15;
      float bias = (col < NH) ? bz[col] : (col < 2 * NH ? br[col - NH] : bb[col - 2 * NH]);
      int mr = m0 + wm * 32 + i * 16 + 4 * l4;
#pragma unroll
      for (int jj = 0; jj < 4; ++jj)
        Gx[(size_t)(mr + jj) * 3072 + col] = f2bf(acc[i][j][jj] + bias);
    }
}

// ===========================================================================
// Per-step phase 1 (round-2 structure, verified; K=1024, Gx-fused, XCD-stable
// swizzle): h @ Bu1-slice -> z (zfb f32) | rh (rhb bf16).
// grid 256: mt = (bid>>3)&7 (32 rows), nt = (bid&7)|((bid>>6)<<3) (64 cols of
// 2048). XCD = bid%8 = nt%8 -> each B-slice pinned to one XCD's L2.
// ===========================================================================
__global__ void __launch_bounds__(256)
p1k(const ushort_t* __restrict__ Bu1, const ushort_t* __restrict__ hb,
    ushort_t* __restrict__ rhb, const float* __restrict__ hf,
    float* __restrict__ zfb, const ushort_t* __restrict__ Gx, int t) {
  __shared__ __align__(16) char smem[24576];
  const int tid  = threadIdx.x;
  const int bid  = blockIdx.x;
  const int lane = tid & 63;
  const int w    = tid >> 6;
  const int wm   = w >> 1, wn = w & 1;
  const int mt   = (bid >> 3) & 7;
  const int nt   = (bid & 7) | ((bid >> 6) << 3);
  const int m0   = mt * 32;
  const int n1   = nt * 64;
  const int l15  = lane & 15, l4 = lane >> 4;
  const bool zside = (n1 < NH);          // block-uniform (64 | 1024)

  // early-issue epilogue operands (Gx is HBM-resident; issue before staging)
  const int mrow = m0 + wm * 16 + 4 * l4;
  const size_t gxrow = (size_t)t * NB * 3072;
  float gxe[2][4], hfe[2][4];
#pragma unroll
  for (int f = 0; f < 2; ++f) {
    int c = n1 + wn * 32 + f * 16 + l15;
#pragma unroll
    for (int jj = 0; jj < 4; ++jj) {
      gxe[f][jj] = bf2f(Gx[gxrow + (size_t)(mrow + jj) * 3072 + c]);
      if (!zside) hfe[f][jj] = hf[(size_t)(mrow + jj) * NH + (c - NH)];
    }
  }

  f32x4 acc0 = {0.f, 0.f, 0.f, 0.f}, acc1 = {0.f, 0.f, 0.f, 0.f};
  for (int kb = 0; kb < 8; ++kb) {       // K = 1024
    const int kbase = kb * BK;
    // stage A (32 x 128) from hb
#pragma unroll
    for (int i = 0; i < 2; ++i) {
      int c = tid + (i << 8);
      int r = c >> 4, kc = (c & 15) << 3;
      i32x4 v = *reinterpret_cast<const i32x4*>(hb + (size_t)(m0 + r) * NH + kbase + kc);
      int off = (r << 8) + (((kc << 1)) ^ ((r & 7) << 4));
      *reinterpret_cast<i32x4*>(&smem[off]) = v;
    }
    // stage B (64 x 128) from Bu1 (stride 1024)
#pragma unroll
    for (int i = 0; i < 4; ++i) {
      int c = tid + (i << 8);
      int n = c >> 4, kc = (c & 15) << 3;
      i32x4 v = *reinterpret_cast<const i32x4*>(Bu1 + (size_t)(n1 + n) * NH + kbase + kc);
      int off = 8192 + (n << 8) + (((kc << 1)) ^ ((n & 7) << 4));
      *reinterpret_cast<i32x4*>(&smem[off]) = v;
    }
    __syncthreads();
#pragma unroll
    for (int ks = 0; ks < 4; ++ks) {
      int kbyte = ks * 64 + l4 * 16;
      int ra = wm * 16 + l15;
      short8 a = *reinterpret_cast<short8*>(&smem[(ra << 8) + (kbyte ^ ((ra & 7) << 4))]);
      int nb0 = wn * 32 + l15;
      short8 b0 = *reinterpret_cast<short8*>(&smem[8192 + (nb0 << 8) + (kbyte ^ ((nb0 & 7) << 4))]);
      int nb1 = nb0 + 16;
      short8 b1 = *reinterpret_cast<short8*>(&smem[8192 + (nb1 << 8) + (kbyte ^ ((nb1 & 7) << 4))]);
      acc0 = __builtin_amdgcn_mfma_f32_16x16x32_bf16(a, b0, acc0, 0, 0, 0);
      acc1 = __builtin_amdgcn_mfma_f32_16x16x32_bf16(a, b1, acc1, 0, 0, 0);
    }
    __syncthreads();
  }
  // epilogue
#pragma unroll
  for (int f = 0; f < 2; ++f) {
    f32x4 av = f ? acc1 : acc0;
    int c = n1 + wn * 32 + f * 16 + l15;
    if (zside) {
#pragma unroll
      for (int jj = 0; jj < 4; ++jj)
        zfb[(size_t)(mrow + jj) * NH + c] = sigmoidf_(av[jj] + gxe[f][jj]);
    } else {
      int cc = c - NH;
#pragma unroll
      for (int jj = 0; jj < 4; ++jj) {
        float rv = sigmoidf_(av[jj] + gxe[f][jj]);
        rhb[(size_t)(mrow + jj) * NH + cc] = f2bf(rv * hfe[f][jj]);
      }
    }
  }
}

// ===========================================================================
// Per-step phase 2: rh @ Bu2-slice -> h_cand; h update.
// grid 256: mt = (bid>>3)&7 (32 rows), nt = (bid&7)|((bid>>6)<<3) (32 cols of
// 1024). Same XCD-stable swizzle.
// ===========================================================================
__global__ void __launch_bounds__(256)
p2k(const ushort_t* __restrict__ Bu2, const ushort_t* __restrict__ rhb,
    ushort_t* __restrict__ hb, float* __restrict__ hf,
    const float* __restrict__ zfb, const ushort_t* __restrict__ Gx,
    float* __restrict__ out, int t) {
  __shared__ __align__(16) char smem[16384];
  const int tid  = threadIdx.x;
  const int bid  = blockIdx.x;
  const int lane = tid & 63;
  const int w    = tid >> 6;
  const int wm   = w >> 1, wn = w & 1;
  const int mt   = (bid >> 3) & 7;
  const int nt   = (bid & 7) | ((bid >> 6) << 3);
  const int m0   = mt * 32;
  const int n2   = nt * 32;
  const int l15  = lane & 15, l4 = lane >> 4;

  // early-issue epilogue operands
  const int mrow = m0 + wm * 16 + 4 * l4;
  const int c    = n2 + wn * 16 + l15;
  const size_t gxrow = (size_t)t * NB * 3072;
  float gxe[4], hfe[4], ze[4];
#pragma unroll
  for (int jj = 0; jj < 4; ++jj) {
    gxe[jj] = bf2f(Gx[gxrow + (size_t)(mrow + jj) * 3072 + 2048 + c]);
    hfe[jj] = hf[(size_t)(mrow + jj) * NH + c];
    ze[jj]  = zfb[(size_t)(mrow + jj) * NH + c];
  }

  f32x4 acc = {0.f, 0.f, 0.f, 0.f};
  for (int kb = 0; kb < 8; ++kb) {       // K = 1024
    const int kbase = kb * BK;
    // stage A (32 x 128) from rhb
#pragma unroll
    for (int i = 0; i < 2; ++i) {
      int cch = tid + (i << 8);
      int r = cch >> 4, kc = (cch & 15) << 3;
      i32x4 v = *reinterpret_cast<const i32x4*>(rhb + (size_t)(m0 + r) * NH + kbase + kc);
      int off = (r << 8) + (((kc << 1)) ^ ((r & 7) << 4));
      *reinterpret_cast<i32x4*>(&smem[off]) = v;
    }
    // stage B (32 x 128) from Bu2 (stride 1024)
#pragma unroll
    for (int i = 0; i < 2; ++i) {
      int cch = tid + (i << 8);
      int n = cch >> 4, kc = (cch & 15) << 3;
      i32x4 v = *reinterpret_cast<const i32x4*>(Bu2 + (size_t)(n2 + n) * NH + kbase + kc);
      int off = 8192 + (n << 8) + (((kc << 1)) ^ ((n & 7) << 4));
      *reinterpret_cast<i32x4*>(&smem[off]) = v;
    }
    __syncthreads();
#pragma unroll
    for (int ks = 0; ks < 4; ++ks) {
      int kbyte = ks * 64 + l4 * 16;
      int ra = wm * 16 + l15;
      short8 a = *reinterpret_cast<short8*>(&smem[(ra << 8) + (kbyte ^ ((ra & 7) << 4))]);
      int nb = wn * 16 + l15;
      short8 b0 = *reinterpret_cast<short8*>(&smem[8192 + (nb << 8) + (kbyte ^ ((nb & 7) << 4))]);
      acc = __builtin_amdgcn_mfma_f32_16x16x32_bf16(a, b0, acc, 0, 0, 0);
    }
    __syncthreads();
  }
  // epilogue: tanh, gate update, publish h
#pragma unroll
  for (int jj = 0; jj < 4; ++jj) {
    size_t idx = (size_t)(mrow + jj) * NH + c;
    float hc = tanhf_(acc[jj] + gxe[jj]);
    float zv = ze[jj];
    float hn = (1.f - zv) * hfe[jj] + zv * hc;
    hf[idx] = hn;
    hb[idx] = f2bf(hn);
    if (t == NT - 1) out[idx] = hn;
  }
}

// ===========================================================================
// ============== FALLBACK (round-2, proven): per-step, K=1536 ===============
// ===========================================================================
__global__ void repack_weights(const float* __restrict__ U,  const float* __restrict__ W,
                               const float* __restrict__ Uz, const float* __restrict__ Wz,
                               const float* __restrict__ Ur, const float* __restrict__ Wr,
                               ushort_t* __restrict__ B1t, ushort_t* __restrict__ B2t) {
  const int kt = blockIdx.x, nt = blockIdx.y, which = blockIdx.z;
  if (which == 1 && nt >= 16) return;
  __shared__ float tile[64][65];
  const int k0 = kt * 64, n0 = nt * 64;
  const int tid = threadIdx.x;
  for (int i = 0; i < 16; ++i) {
    int e = tid + i * 256;
    int r = e >> 6, c = e & 63;
    int k = k0 + r, n = n0 + c;
    int nn = n & 1023;
    const float* src;
    if (which == 0) {
      if (k < NH) src = (n < NH ? Uz : Ur) + (size_t)k * NH + nn;
      else        src = (n < NH ? Wz : Wr) + (size_t)(k - NH) * NH + nn;
    } else {
      if (k < NH) src = U + (size_t)k * NH + nn;
      else        src = W + (size_t)(k - NH) * NH + nn;
    }
    tile[r][c] = *src;
  }
  __syncthreads();
  ushort_t* dst = (which == 0) ? B1t : B2t;
  for (int i = 0; i < 2; ++i) {
    int cch = tid + i * 256;
    int nl = cch >> 3, kc = (cch & 7) * 8;
    ushort_t tmp[8];
#pragma unroll
    for (int j = 0; j < 8; ++j) tmp[j] = f2bf(tile[kc + j][nl]);
    *reinterpret_cast<i32x4*>(dst + (size_t)(n0 + nl) * KK + k0 + kc) =
        *reinterpret_cast<i32x4*>(tmp);
  }
}

__global__ void __launch_bounds__(256)
gru_phase1(const float* __restrict__ x, const ushort_t* __restrict__ B1t,
           const ushort_t* __restrict__ hb, ushort_t* __restrict__ rhb,
           const float* __restrict__ hf, float* __restrict__ zfb,
           const float* __restrict__ bz, const float* __restrict__ br, int t) {
  __shared__ __align__(16) char smem[24576];
  const int tid  = threadIdx.x;
  const int bid  = blockIdx.x;
  const int lane = tid & 63;
  const int w    = tid >> 6;
  const int wm   = w >> 1, wn = w & 1;
  const int m0   = (bid >> 5) * 32;
  const int n1   = (bid & 31) * 64;
  const int l15  = lane & 15, l4 = lane >> 4;

  f32x4 acc0 = {0.f, 0.f, 0.f, 0.f}, acc1 = {0.f, 0.f, 0.f, 0.f};
  for (int kb = 0; kb < KK / BK; ++kb) {
    const int kbase = kb * BK;
#pragma unroll
    for (int i = 0; i < 2; ++i) {
      int c = tid + (i << 8);
      int r = c >> 4, kc = (c & 15) << 3;
      int m = m0 + r, k = kbase + kc;
      i32x4 v;
      if (k < NH) {
        v = *reinterpret_cast<const i32x4*>(hb + (size_t)m * NH + k);
      } else {
        const float* xp = x + (size_t)m * (NT * ND) + (size_t)t * ND + (k - NH);
        f32x4 f0 = *reinterpret_cast<const f32x4*>(xp);
        f32x4 f1 = *reinterpret_cast<const f32x4*>(xp + 4);
        v[0] = pack2(f0[0], f0[1]); v[1] = pack2(f0[2], f0[3]);
        v[2] = pack2(f1[0], f1[1]); v[3] = pack2(f1[2], f1[3]);
      }
      int off = (r << 8) + (((kc << 1)) ^ ((r & 7) << 4));
      *reinterpret_cast<i32x4*>(&smem[off]) = v;
    }
#pragma unroll
    for (int i = 0; i < 4; ++i) {
      int c = tid + (i << 8);
      int n = c >> 4, kc = (c & 15) << 3;
      i32x4 v = *reinterpret_cast<const i32x4*>(B1t + (size_t)(n1 + n) * KK + kbase + kc);
      int off = 8192 + (n << 8) + (((kc << 1)) ^ ((n & 7) << 4));
      *reinterpret_cast<i32x4*>(&smem[off]) = v;
    }
    __syncthreads();
#pragma unroll
    for (int ks = 0; ks < 4; ++ks) {
      int kbyte = ks * 64 + l4 * 16;
      int ra = wm * 16 + l15;
      short8 a = *reinterpret_cast<short8*>(&smem[(ra << 8) + (kbyte ^ ((ra & 7) << 4))]);
      int nb0 = wn * 32 + l15;
      short8 b0 = *reinterpret_cast<short8*>(&smem[8192 + (nb0 << 8) + (kbyte ^ ((nb0 & 7) << 4))]);
      int nb1 = nb0 + 16;
      short8 b1 = *reinterpret_cast<short8*>(&smem[8192 + (nb1 << 8) + (kbyte ^ ((nb1 & 7) << 4))]);
      acc0 = __builtin_amdgcn_mfma_f32_16x16x32_bf16(a, b0, acc0, 0, 0, 0);
      acc1 = __builtin_amdgcn_mfma_f32_16x16x32_bf16(a, b1, acc1, 0, 0, 0);
    }
    __syncthreads();
  }
  int mrow = m0 + wm * 16 + l4 * 4;
#pragma unroll
  for (int f = 0; f < 2; ++f) {
    f32x4 av = f ? acc1 : acc0;
    int c = n1 + wn * 32 + f * 16 + l15;
#pragma unroll
    for (int j = 0; j < 4; ++j) {
      int m = mrow + j;
      float v = av[j];
      if (c < NH) {
        zfb[(size_t)m * NH + c] = sigmoidf_(v + bz[c]);
      } else {
        int cc = c - NH;
        float rv = sigmoidf_(v + br[cc]);
        rhb[(size_t)m * NH + cc] = f2bf(rv * hf[(size_t)m * NH + cc]);
      }
    }
  }
}

__global__ void __launch_bounds__(256)
gru_phase2(const float* __restrict__ x, const ushort_t* __restrict__ B2t,
           ushort_t* __restrict__ hb, const ushort_t* __restrict__ rhb,
           float* __restrict__ hf, const float* __restrict__ zfb,
           const float* __restrict__ bb, float* __restrict__ out, int t) {
  __shared__ __align__(16) char smem[16384];
  const int tid  = threadIdx.x;
  const int bid  = blockIdx.x;
  const int lane = tid & 63;
  const int w    = tid >> 6;
  const int wm   = w >> 1, wn = w & 1;
  const int m0   = (bid >> 5) * 32;
  const int n2   = (bid & 31) * 32;
  const int l15  = lane & 15, l4 = lane >> 4;

  f32x4 acc = {0.f, 0.f, 0.f, 0.f};
  for (int kb = 0; kb < KK / BK; ++kb) {
    const int kbase = kb * BK;
#pragma unroll
    for (int i = 0; i < 2; ++i) {
      int c = tid + (i << 8);
      int r = c >> 4, kc = (c & 15) << 3;
      int m = m0 + r, k = kbase + kc;
      i32x4 v;
      if (k < NH) {
        v = *reinterpret_cast<const i32x4*>(rhb + (size_t)m * NH + k);
      } else {
        const float* xp = x + (size_t)m * (NT * ND) + (size_t)t * ND + (k - NH);
        f32x4 f0 = *reinterpret_cast<const f32x4*>(xp);
        f32x4 f1 = *reinterpret_cast<const f32x4*>(xp + 4);
        v[0] = pack2(f0[0], f0[1]); v[1] = pack2(f0[2], f0[3]);
        v[2] = pack2(f1[0], f1[1]); v[3] = pack2(f1[2], f1[3]);
      }
      int off = (r << 8) + (((kc << 1)) ^ ((r & 7) << 4));
      *reinterpret_cast<i32x4*>(&smem[off]) = v;
    }
#pragma unroll
    for (int i = 0; i < 2; ++i) {
      int c = tid + (i << 8);
      int n = c >> 4, kc = (c & 15) << 3;
      i32x4 v = *reinterpret_cast<const i32x4*>(B2t + (size_t)(n2 + n) * KK + kbase + kc);
      int off = 8192 + (n << 8) + (((kc << 1)) ^ ((n & 7) << 4));
      *reinterpret_cast<i32x4*>(&smem[off]) = v;
    }
    __syncthreads();
#pragma unroll
    for (int ks = 0; ks < 4; ++ks) {
      int kbyte = ks * 64 + l4 * 16;
      int ra = wm * 16 + l15;
      short8 a = *reinterpret_cast<short8*>(&smem[(ra << 8) + (kbyte ^ ((ra & 7) << 4))]);
      int nb = wn * 16 + l15;
      short8 b0 = *reinterpret_cast<short8*>(&smem[8192 + (nb << 8) + (kbyte ^ ((nb & 7) << 4))]);
      acc = __builtin_amdgcn_mfma_f32_16x16x32_bf16(a, b0, acc, 0, 0, 0);
    }
    __syncthreads();
  }
  int mrow = m0 + wm * 16 + l4 * 4;
  int c = n2 + wn * 16 + l15;
#pragma unroll
  for (int j = 0; j < 4; ++j) {
    int m = mrow + j;
    size_t idx = (size_t)m * NH + c;
    float hc = tanhf_(acc[j] + bb[c]);
    float zv = zfb[idx];
    float hn = (1.f - zv) * hf[idx] + zv * hc;
    hf[idx] = hn;
    hb[idx] = f2bf(hn);
    if (t == NT - 1) out[idx] = hn;
  }
}

// ===========================================================================
extern "C" void kernel_launch(void* const* d_in, const int* in_sizes, int n_in,
                              void* d_out, int out_size, void* d_ws, size_t ws_size,
                              hipStream_t stream) {
  const float* x  = (const float*)d_in[0];
  const float* W  = (const float*)d_in[1];
  const float* U  = (const float*)d_in[2];
  const float* Wz = (const float*)d_in[3];
  const float* Uz = (const float*)d_in[4];
  const float* Wr = (const float*)d_in[5];
  const float* Ur = (const float*)d_in[6];
  const float* bb = (const float*)d_in[7];
  const float* bz = (const float*)d_in[8];
  const float* br = (const float*)d_in[9];
  float* out = (float*)d_out;
  char* ws = (char*)d_ws;

  // fast-path workspace layout (same offsets as r6-r8)
  ushort_t* Bu1   = (ushort_t*)(ws);                  //  4,194,304
  ushort_t* Bu2   = (ushort_t*)(ws + 4194304);        //  2,097,152
  ushort_t* Bx    = (ushort_t*)(ws + 6291456);        //  3,145,728
  ushort_t* hb    = (ushort_t*)(ws + 9437184);        //    524,288
  ushort_t* rhb   = (ushort_t*)(ws + 9961472);        //    524,288
  float*    hf    = (float*)   (ws + 10485760);       //  1,048,576
  float*    zfb   = (float*)   (ws + 11534336);       //  1,048,576
  ushort_t* Gx    = (ushort_t*)(ws + 12587008);       // 805,306,368 -> 817,893,376

  const bool fast = (ws_size >= (size_t)817893376ULL);

  if (fast) {
    hipLaunchKernelGGL(repackT, dim3(16, 16), dim3(256), 0, stream, Uz, Bu1, NH);
    hipLaunchKernelGGL(repackT, dim3(16, 16), dim3(256), 0, stream, Ur, Bu1 + (size_t)NH * NH, NH);
    hipLaunchKernelGGL(repackT, dim3(16, 16), dim3(256), 0, stream, U,  Bu2, NH);
    hipLaunchKernelGGL(repackT, dim3(8, 16),  dim3(256), 0, stream, Wz, Bx, ND);
    hipLaunchKernelGGL(repackT, dim3(8, 16),  dim3(256), 0, stream, Wr, Bx + (size_t)NH * ND, ND);
    hipLaunchKernelGGL(repackT, dim3(8, 16),  dim3(256), 0, stream, W,  Bx + (size_t)2 * NH * ND, ND);
    hipLaunchKernelGGL(init_state, dim3(1024), dim3(256), 0, stream, hb, hf);
    hipLaunchKernelGGL(gxgemm, dim3(2048, 48), dim3(256), 0, stream, x, Bx, bz, br, bb, Gx);
    for (int t = 0; t < NT; ++t) {
      hipLaunchKernelGGL(p1k, dim3(256), dim3(256), 0, stream,
                         Bu1, hb, rhb, hf, zfb, Gx, t);
      hipLaunchKernelGGL(p2k, dim3(256), dim3(256), 0, stream,
                         Bu2, rhb, hb, hf, zfb, Gx, out, t);
    }
  } else {
    // fallback: proven round-2 per-step path (K=1536, biases in-loop)
    ushort_t* B1t  = (ushort_t*)(ws);
    ushort_t* B2t  = (ushort_t*)(ws + 6291456);
    ushort_t* hb2  = (ushort_t*)(ws + 9437184);
    ushort_t* rhb2 = (ushort_t*)(ws + 9961472);
    float*    hf2  = (float*)   (ws + 10485760);
    float*    zfb2 = (float*)   (ws + 11534336);
    hipLaunchKernelGGL(repack_weights, dim3(24, 32, 2), dim3(256), 0, stream,
                       U, W, Uz, Wz, Ur, Wr, B1t, B2t);
    hipLaunchKernelGGL(init_state, dim3(1024), dim3(256), 0, stream, hb2, hf2);
    for (int t = 0; t < NT; ++t) {
      hipLaunchKernelGGL(gru_phase1, dim3(256), dim3(256), 0, stream,
                         x, B1t, hb2, rhb2, hf2, zfb2, bz, br, t);
      hipLaunchKernelGGL(gru_phase2, dim3(256), dim3(256), 0, stream,
                         x, B2t, hb2, rhb2, hf2, zfb2, bb, out, t);
    }
  }
}

// Round 10
// 8818.150 us; speedup vs baseline: 3.8648x; 1.3780x over previous
//
#include <hip/hip_runtime.h>

typedef unsigned short ushort_t;
typedef __attribute__((ext_vector_type(8))) short short8;
typedef __attribute__((ext_vector_type(4))) float f32x4;
typedef __attribute__((ext_vector_type(4))) int i32x4;

#define NB   256     // batch
#define NT   512     // timesteps
#define ND   512     // input dim
#define NH   1024    // hidden dim
#define KK   1536    // NH + ND (fallback path concat K)
#define BK   128

__device__ __forceinline__ ushort_t f2bf(float f) {
  union { float f; unsigned u; } v; v.f = f;
  unsigned u = v.u;
  return (ushort_t)((u + 0x7FFFu + ((u >> 16) & 1u)) >> 16);
}
__device__ __forceinline__ int pack2(float a, float b) {
  return (int)(((unsigned)f2bf(b) << 16) | (unsigned)f2bf(a));
}
__device__ __forceinline__ float bf2f(ushort_t h) {
  union { unsigned u; float f; } v; v.u = ((unsigned)h) << 16; return v.f;
}
__device__ __forceinline__ float sigmoidf_(float x) {
  return 1.f / (1.f + __expf(-x));
}
__device__ __forceinline__ float tanhf_(float x) {
  return 1.f - 2.f / (__expf(2.f * x) + 1.f);
}

// ===========================================================================
// Transpose-repack (verified r6-r9): src f32 [K][1024] -> dst bf16 [1024][K].
// ===========================================================================
__global__ void repackT(const float* __restrict__ src, ushort_t* __restrict__ dst,
                        int K) {
  __shared__ float tile[64][65];
  const int k0 = blockIdx.x * 64, n0 = blockIdx.y * 64;
  const int tid = threadIdx.x;
  for (int i = 0; i < 16; ++i) {
    int e = tid + i * 256;
    int r = e >> 6, c = e & 63;
    tile[r][c] = src[(size_t)(k0 + r) * 1024 + n0 + c];
  }
  __syncthreads();
  for (int i = 0; i < 2; ++i) {
    int cch = tid + i * 256;
    int nl = cch >> 3, kc = (cch & 7) * 8;
    ushort_t tmp[8];
#pragma unroll
    for (int j = 0; j < 8; ++j) tmp[j] = f2bf(tile[kc + j][nl]);
    *reinterpret_cast<i32x4*>(dst + (size_t)(n0 + nl) * K + k0 + kc) =
        *reinterpret_cast<i32x4*>(tmp);
  }
}

__global__ void init_state(ushort_t* __restrict__ hb, float* __restrict__ hf) {
  int i = blockIdx.x * 256 + threadIdx.x;
  if (i < NB * NH) { hb[i] = 0; hf[i] = 0.f; }
}

// ===========================================================================
// Gx precompute (verified r6-r9): Gx[t*256+b][j], j: 0..1023=z, 1024..2047=r,
// 2048..3071=cand. Bx bf16 [3072][512] n-major.
// ===========================================================================
__global__ void __launch_bounds__(256)
gxgemm(const float* __restrict__ x, const ushort_t* __restrict__ Bx,
       const float* __restrict__ bz, const float* __restrict__ br,
       const float* __restrict__ bb, ushort_t* __restrict__ Gx) {
  __shared__ __align__(16) char smem[32768];
  const int tid  = threadIdx.x;
  const int m0   = blockIdx.x * 64;
  const int n0   = blockIdx.y * 64;
  const int lane = tid & 63;
  const int w    = tid >> 6;
  const int wm   = w >> 1, wn = w & 1;
  const int l15  = lane & 15, l4 = lane >> 4;

  f32x4 acc[2][2];
#pragma unroll
  for (int i = 0; i < 2; ++i)
#pragma unroll
    for (int j = 0; j < 2; ++j) acc[i][j] = (f32x4){0.f, 0.f, 0.f, 0.f};

  for (int kb = 0; kb < 4; ++kb) {
    const int kbase = kb * BK;
#pragma unroll
    for (int i = 0; i < 4; ++i) {
      int c = tid + (i << 8);
      int r = c >> 4, kc = (c & 15) << 3;
      int m = m0 + r;
      int tt = m >> 8, b = m & 255;
      const float* xp = x + ((size_t)b * NT + tt) * ND + kbase + kc;
      f32x4 f0 = *reinterpret_cast<const f32x4*>(xp);
      f32x4 f1 = *reinterpret_cast<const f32x4*>(xp + 4);
      i32x4 v;
      v[0] = pack2(f0[0], f0[1]); v[1] = pack2(f0[2], f0[3]);
      v[2] = pack2(f1[0], f1[1]); v[3] = pack2(f1[2], f1[3]);
      int off = (r << 8) + (((kc << 1)) ^ ((r & 7) << 4));
      *reinterpret_cast<i32x4*>(&smem[off]) = v;
    }
#pragma unroll
    for (int i = 0; i < 4; ++i) {
      int c = tid + (i << 8);
      int n = c >> 4, kc = (c & 15) << 3;
      i32x4 v = *reinterpret_cast<const i32x4*>(Bx + (size_t)(n0 + n) * 512 + kbase + kc);
      int off = 16384 + (n << 8) + (((kc << 1)) ^ ((n & 7) << 4));
      *reinterpret_cast<i32x4*>(&smem[off]) = v;
    }
    __syncthreads();
#pragma unroll
    for (int ks = 0; ks < 4; ++ks) {
      int kbyte = ks * 64 + l4 * 16;
      short8 a[2], b[2];
#pragma unroll
      for (int i = 0; i < 2; ++i) {
        int ra = wm * 32 + i * 16 + l15;
        a[i] = *reinterpret_cast<short8*>(&smem[(ra << 8) + (kbyte ^ ((ra & 7) << 4))]);
        int nb = wn * 32 + i * 16 + l15;
        b[i] = *reinterpret_cast<short8*>(&smem[16384 + (nb << 8) + (kbyte ^ ((nb & 7) << 4))]);
      }
#pragma unroll
      for (int i = 0; i < 2; ++i)
#pragma unroll
        for (int j = 0; j < 2; ++j)
          acc[i][j] = __builtin_amdgcn_mfma_f32_16x16x32_bf16(a[i], b[j], acc[i][j], 0, 0, 0);
    }
    __syncthreads();
  }
#pragma unroll
  for (int i = 0; i < 2; ++i)
#pragma unroll
    for (int j = 0; j < 2; ++j) {
      int col = n0 + wn * 32 + j * 16 + l15;
      float bias = (col < NH) ? bz[col] : (col < 2 * NH ? br[col - NH] : bb[col - 2 * NH]);
      int mr = m0 + wm * 32 + i * 16 + 4 * l4;
#pragma unroll
      for (int jj = 0; jj < 4; ++jj)
        Gx[(size_t)(mr + jj) * 3072 + col] = f2bf(acc[i][j][jj] + bias);
    }
}

// ===========================================================================
// Phase 1 v2: 512 thr (8 waves, 2/SIMD), grid 256 = 16 mt(16 rows) x 16 nt
// (128 cols of 2048). XCD-pinned: nt%8 = bid%8. Double-buffered reg-staged
// LDS (72KB dynamic), 1 barrier/K-iter. Wave w: cols nt*128+16w, full K=1024.
// ===========================================================================
__global__ void __launch_bounds__(512)
p1k2(const ushort_t* __restrict__ Bu1, const ushort_t* __restrict__ hb,
     ushort_t* __restrict__ rhb, const float* __restrict__ hf,
     float* __restrict__ zfb, const ushort_t* __restrict__ Gx, int t) {
  extern __shared__ __align__(16) char dsm[];   // 2 x (4KB A + 32KB B) = 73728
  const int tid  = threadIdx.x;
  const int bid  = blockIdx.x;
  const int lane = tid & 63;
  const int w    = tid >> 6;
  const int l15  = lane & 15, l4 = lane >> 4;
  const int nt   = (bid & 7) | ((bid >> 7) << 3);
  const int mt   = (bid >> 3) & 15;
  const int m0   = mt * 16;
  const int n1   = nt * 128;
  const bool zside = (n1 < NH);          // block-uniform

  // early-issue epilogue operands
  const int mrow = m0 + 4 * l4;
  const int col1 = n1 + w * 16 + l15;
  const size_t gxrow = (size_t)t * NB * 3072;
  float gxe[4], hfe[4];
#pragma unroll
  for (int jj = 0; jj < 4; ++jj) {
    gxe[jj] = bf2f(Gx[gxrow + (size_t)(mrow + jj) * 3072 + col1]);
    if (!zside) hfe[jj] = hf[(size_t)(mrow + jj) * NH + (col1 - NH)];
  }

  // staging regs
  i32x4 ra;      // A chunk (tid < 256)
  i32x4 rb[4];   // B chunks
  const int akc8 = tid & 15, ar = tid >> 4;          // A chunk coords (tid<256)

#define P1_LOAD(kb_) do {                                                     \
    int kbase_ = (kb_) * BK;                                                  \
    if (tid < 256)                                                            \
      ra = *reinterpret_cast<const i32x4*>(                                   \
          hb + (size_t)(m0 + ar) * NH + kbase_ + akc8 * 8);                   \
    _Pragma("unroll")                                                         \
    for (int i_ = 0; i_ < 4; ++i_) {                                          \
      int c_ = tid + i_ * 512;                                                \
      int kc8_ = c_ & 15, col_ = c_ >> 4;                                     \
      rb[i_] = *reinterpret_cast<const i32x4*>(                               \
          Bu1 + (size_t)(n1 + col_) * NH + kbase_ + kc8_ * 8);                \
    }                                                                         \
  } while (0)

#define P1_WRITE(p_) do {                                                     \
    char* base_ = dsm + (p_) * 36864;                                         \
    if (tid < 256)                                                            \
      *reinterpret_cast<i32x4*>(base_ +                                       \
          (((akc8 * 16 + ar) * 16) ^ ((akc8 & 7) << 4))) = ra;                \
    _Pragma("unroll")                                                         \
    for (int i_ = 0; i_ < 4; ++i_) {                                          \
      int c_ = tid + i_ * 512;                                                \
      int kc8_ = c_ & 15, col_ = c_ >> 4;                                     \
      *reinterpret_cast<i32x4*>(base_ + 4096 +                                \
          (((kc8_ * 128 + col_) * 16) ^ ((kc8_ & 7) << 4))) = rb[i_];         \
    }                                                                         \
  } while (0)

  f32x4 acc = {0.f, 0.f, 0.f, 0.f};
  P1_LOAD(0);
#pragma unroll
  for (int kb = 0; kb < 8; ++kb) {
    const int p = kb & 1;
    P1_WRITE(p);
    if (kb < 7) P1_LOAD(kb + 1);
    __syncthreads();
    char* base = dsm + p * 36864;
#pragma unroll
    for (int ks = 0; ks < 4; ++ks) {
      int kc8 = ks * 4 + l4;
      short8 a = *reinterpret_cast<short8*>(base +
          (((kc8 * 16 + l15) * 16) ^ ((kc8 & 7) << 4)));
      short8 b = *reinterpret_cast<short8*>(base + 4096 +
          (((kc8 * 128 + w * 16 + l15) * 16) ^ ((kc8 & 7) << 4)));
      acc = __builtin_amdgcn_mfma_f32_16x16x32_bf16(a, b, acc, 0, 0, 0);
    }
    // one barrier per iter: safe (buf p reused only after sync(kb+1))
  }
#undef P1_LOAD
#undef P1_WRITE

  // epilogue
  if (zside) {
#pragma unroll
    for (int jj = 0; jj < 4; ++jj)
      zfb[(size_t)(mrow + jj) * NH + col1] = sigmoidf_(acc[jj] + gxe[jj]);
  } else {
    int cc = col1 - NH;
#pragma unroll
    for (int jj = 0; jj < 4; ++jj) {
      float rv = sigmoidf_(acc[jj] + gxe[jj]);
      rhb[(size_t)(mrow + jj) * NH + cc] = f2bf(rv * hfe[jj]);
    }
  }
}

// ===========================================================================
// Phase 2 v2: 512 thr (8 waves), grid 256 = 16 mt(16 rows) x 16 nt(64 cols).
// Wave (ct=w&3, kh=w>>2): cols nt*64+16ct, K-half kh*512 -> 16 MFMA; pair
// reduction via LDS. Double-buffered staging (40KB static).
// ===========================================================================
__global__ void __launch_bounds__(512)
p2k2(const ushort_t* __restrict__ Bu2, const ushort_t* __restrict__ rhb,
     ushort_t* __restrict__ hb, float* __restrict__ hf,
     const float* __restrict__ zfb, const ushort_t* __restrict__ Gx,
     float* __restrict__ out, int t) {
  __shared__ __align__(16) char smem[40960];    // 2 x (4KB A + 16KB B)
  const int tid  = threadIdx.x;
  const int bid  = blockIdx.x;
  const int lane = tid & 63;
  const int w    = tid >> 6;
  const int l15  = lane & 15, l4 = lane >> 4;
  const int ct   = w & 3, kh = w >> 2;
  const int nt   = (bid & 7) | ((bid >> 7) << 3);
  const int mt   = (bid >> 3) & 15;
  const int m0   = mt * 16;
  const int n2   = nt * 64;

  // early-issue epilogue operands (waves 0..3 own the output tiles)
  const int mrow = m0 + 4 * l4;
  const int col  = n2 + ct * 16 + l15;
  const size_t gxrow = (size_t)t * NB * 3072;
  float gxe[4], hfe[4], ze[4];
  if (w < 4) {
#pragma unroll
    for (int jj = 0; jj < 4; ++jj) {
      gxe[jj] = bf2f(Gx[gxrow + (size_t)(mrow + jj) * 3072 + 2048 + col]);
      hfe[jj] = hf[(size_t)(mrow + jj) * NH + col];
      ze[jj]  = zfb[(size_t)(mrow + jj) * NH + col];
    }
  }

  i32x4 ra;
  i32x4 rb[2];
  const int akc8 = tid & 15, ar = tid >> 4;

#define P2_LOAD(kb_) do {                                                     \
    int kbase_ = (kb_) * BK;                                                  \
    if (tid < 256)                                                            \
      ra = *reinterpret_cast<const i32x4*>(                                   \
          rhb + (size_t)(m0 + ar) * NH + kbase_ + akc8 * 8);                  \
    _Pragma("unroll")                                                         \
    for (int i_ = 0; i_ < 2; ++i_) {                                          \
      int c_ = tid + i_ * 512;                                                \
      int kc8_ = c_ & 15, col_ = c_ >> 4;                                     \
      rb[i_] = *reinterpret_cast<const i32x4*>(                               \
          Bu2 + (size_t)(n2 + col_) * NH + kbase_ + kc8_ * 8);                \
    }                                                                         \
  } while (0)

#define P2_WRITE(p_) do {                                                     \
    char* base_ = smem + (p_) * 20480;                                        \
    if (tid < 256)                                                            \
      *reinterpret_cast<i32x4*>(base_ +                                       \
          (((akc8 * 16 + ar) * 16) ^ ((akc8 & 7) << 4))) = ra;                \
    _Pragma("unroll")                                                         \
    for (int i_ = 0; i_ < 2; ++i_) {                                          \
      int c_ = tid + i_ * 512;                                                \
      int kc8_ = c_ & 15, col_ = c_ >> 4;                                     \
      *reinterpret_cast<i32x4*>(base_ + 4096 +                                \
          (((kc8_ * 64 + col_) * 16) ^ ((kc8_ & 7) << 4))) = rb[i_];          \
    }                                                                         \
  } while (0)

  f32x4 acc = {0.f, 0.f, 0.f, 0.f};
  P2_LOAD(0);
#pragma unroll
  for (int kb = 0; kb < 8; ++kb) {
    const int p = kb & 1;
    P2_WRITE(p);
    if (kb < 7) P2_LOAD(kb + 1);
    __syncthreads();
    char* base = smem + p * 20480;
#pragma unroll
    for (int ks2 = 0; ks2 < 2; ++ks2) {
      int ks = kh * 2 + ks2;
      int kc8 = ks * 4 + l4;
      short8 a = *reinterpret_cast<short8*>(base +
          (((kc8 * 16 + l15) * 16) ^ ((kc8 & 7) << 4)));
      short8 b = *reinterpret_cast<short8*>(base + 4096 +
          (((kc8 * 64 + ct * 16 + l15) * 16) ^ ((kc8 & 7) << 4)));
      acc = __builtin_amdgcn_mfma_f32_16x16x32_bf16(a, b, acc, 0, 0, 0);
    }
  }
#undef P2_LOAD
#undef P2_WRITE

  // cross-wave K-half reduction (waves w and w+4 share a tile)
  __syncthreads();
  *reinterpret_cast<f32x4*>(smem + w * 1024 + lane * 16) = acc;
  __syncthreads();
  if (w < 4) {
    f32x4 v = acc + *reinterpret_cast<f32x4*>(smem + (w + 4) * 1024 + lane * 16);
#pragma unroll
    for (int jj = 0; jj < 4; ++jj) {
      size_t idx = (size_t)(mrow + jj) * NH + col;
      float hc = tanhf_(v[jj] + gxe[jj]);
      float zv = ze[jj];
      float hn = (1.f - zv) * hfe[jj] + zv * hc;
      hf[idx] = hn;
      hb[idx] = f2bf(hn);
      if (t == NT - 1) out[idx] = hn;
    }
  }
}

// ===========================================================================
// ============== FALLBACK (round-2, proven): per-step, K=1536 ===============
// ===========================================================================
__global__ void repack_weights(const float* __restrict__ U,  const float* __restrict__ W,
                               const float* __restrict__ Uz, const float* __restrict__ Wz,
                               const float* __restrict__ Ur, const float* __restrict__ Wr,
                               ushort_t* __restrict__ B1t, ushort_t* __restrict__ B2t) {
  const int kt = blockIdx.x, nt = blockIdx.y, which = blockIdx.z;
  if (which == 1 && nt >= 16) return;
  __shared__ float tile[64][65];
  const int k0 = kt * 64, n0 = nt * 64;
  const int tid = threadIdx.x;
  for (int i = 0; i < 16; ++i) {
    int e = tid + i * 256;
    int r = e >> 6, c = e & 63;
    int k = k0 + r, n = n0 + c;
    int nn = n & 1023;
    const float* src;
    if (which == 0) {
      if (k < NH) src = (n < NH ? Uz : Ur) + (size_t)k * NH + nn;
      else        src = (n < NH ? Wz : Wr) + (size_t)(k - NH) * NH + nn;
    } else {
      if (k < NH) src = U + (size_t)k * NH + nn;
      else        src = W + (size_t)(k - NH) * NH + nn;
    }
    tile[r][c] = *src;
  }
  __syncthreads();
  ushort_t* dst = (which == 0) ? B1t : B2t;
  for (int i = 0; i < 2; ++i) {
    int cch = tid + i * 256;
    int nl = cch >> 3, kc = (cch & 7) * 8;
    ushort_t tmp[8];
#pragma unroll
    for (int j = 0; j < 8; ++j) tmp[j] = f2bf(tile[kc + j][nl]);
    *reinterpret_cast<i32x4*>(dst + (size_t)(n0 + nl) * KK + k0 + kc) =
        *reinterpret_cast<i32x4*>(tmp);
  }
}

__global__ void __launch_bounds__(256)
gru_phase1(const float* __restrict__ x, const ushort_t* __restrict__ B1t,
           const ushort_t* __restrict__ hb, ushort_t* __restrict__ rhb,
           const float* __restrict__ hf, float* __restrict__ zfb,
           const float* __restrict__ bz, const float* __restrict__ br, int t) {
  __shared__ __align__(16) char smem[24576];
  const int tid  = threadIdx.x;
  const int bid  = blockIdx.x;
  const int lane = tid & 63;
  const int w    = tid >> 6;
  const int wm   = w >> 1, wn = w & 1;
  const int m0   = (bid >> 5) * 32;
  const int n1   = (bid & 31) * 64;
  const int l15  = lane & 15, l4 = lane >> 4;

  f32x4 acc0 = {0.f, 0.f, 0.f, 0.f}, acc1 = {0.f, 0.f, 0.f, 0.f};
  for (int kb = 0; kb < KK / BK; ++kb) {
    const int kbase = kb * BK;
#pragma unroll
    for (int i = 0; i < 2; ++i) {
      int c = tid + (i << 8);
      int r = c >> 4, kc = (c & 15) << 3;
      int m = m0 + r, k = kbase + kc;
      i32x4 v;
      if (k < NH) {
        v = *reinterpret_cast<const i32x4*>(hb + (size_t)m * NH + k);
      } else {
        const float* xp = x + (size_t)m * (NT * ND) + (size_t)t * ND + (k - NH);
        f32x4 f0 = *reinterpret_cast<const f32x4*>(xp);
        f32x4 f1 = *reinterpret_cast<const f32x4*>(xp + 4);
        v[0] = pack2(f0[0], f0[1]); v[1] = pack2(f0[2], f0[3]);
        v[2] = pack2(f1[0], f1[1]); v[3] = pack2(f1[2], f1[3]);
      }
      int off = (r << 8) + (((kc << 1)) ^ ((r & 7) << 4));
      *reinterpret_cast<i32x4*>(&smem[off]) = v;
    }
#pragma unroll
    for (int i = 0; i < 4; ++i) {
      int c = tid + (i << 8);
      int n = c >> 4, kc = (c & 15) << 3;
      i32x4 v = *reinterpret_cast<const i32x4*>(B1t + (size_t)(n1 + n) * KK + kbase + kc);
      int off = 8192 + (n << 8) + (((kc << 1)) ^ ((n & 7) << 4));
      *reinterpret_cast<i32x4*>(&smem[off]) = v;
    }
    __syncthreads();
#pragma unroll
    for (int ks = 0; ks < 4; ++ks) {
      int kbyte = ks * 64 + l4 * 16;
      int ra = wm * 16 + l15;
      short8 a = *reinterpret_cast<short8*>(&smem[(ra << 8) + (kbyte ^ ((ra & 7) << 4))]);
      int nb0 = wn * 32 + l15;
      short8 b0 = *reinterpret_cast<short8*>(&smem[8192 + (nb0 << 8) + (kbyte ^ ((nb0 & 7) << 4))]);
      int nb1 = nb0 + 16;
      short8 b1 = *reinterpret_cast<short8*>(&smem[8192 + (nb1 << 8) + (kbyte ^ ((nb1 & 7) << 4))]);
      acc0 = __builtin_amdgcn_mfma_f32_16x16x32_bf16(a, b0, acc0, 0, 0, 0);
      acc1 = __builtin_amdgcn_mfma_f32_16x16x32_bf16(a, b1, acc1, 0, 0, 0);
    }
    __syncthreads();
  }
  int mrow = m0 + wm * 16 + l4 * 4;
#pragma unroll
  for (int f = 0; f < 2; ++f) {
    f32x4 av = f ? acc1 : acc0;
    int c = n1 + wn * 32 + f * 16 + l15;
#pragma unroll
    for (int j = 0; j < 4; ++j) {
      int m = mrow + j;
      float v = av[j];
      if (c < NH) {
        zfb[(size_t)m * NH + c] = sigmoidf_(v + bz[c]);
      } else {
        int cc = c - NH;
        float rv = sigmoidf_(v + br[cc]);
        rhb[(size_t)m * NH + cc] = f2bf(rv * hf[(size_t)m * NH + cc]);
      }
    }
  }
}

__global__ void __launch_bounds__(256)
gru_phase2(const float* __restrict__ x, const ushort_t* __restrict__ B2t,
           ushort_t* __restrict__ hb, const ushort_t* __restrict__ rhb,
           float* __restrict__ hf, const float* __restrict__ zfb,
           const float* __restrict__ bb, float* __restrict__ out, int t) {
  __shared__ __align__(16) char smem[16384];
  const int tid  = threadIdx.x;
  const int bid  = blockIdx.x;
  const int lane = tid & 63;
  const int w    = tid >> 6;
  const int wm   = w >> 1, wn = w & 1;
  const int m0   = (bid >> 5) * 32;
  const int n2   = (bid & 31) * 32;
  const int l15  = lane & 15, l4 = lane >> 4;

  f32x4 acc = {0.f, 0.f, 0.f, 0.f};
  for (int kb = 0; kb < KK / BK; ++kb) {
    const int kbase = kb * BK;
#pragma unroll
    for (int i = 0; i < 2; ++i) {
      int c = tid + (i << 8);
      int r = c >> 4, kc = (c & 15) << 3;
      int m = m0 + r, k = kbase + kc;
      i32x4 v;
      if (k < NH) {
        v = *reinterpret_cast<const i32x4*>(rhb + (size_t)m * NH + k);
      } else {
        const float* xp = x + (size_t)m * (NT * ND) + (size_t)t * ND + (k - NH);
        f32x4 f0 = *reinterpret_cast<const f32x4*>(xp);
        f32x4 f1 = *reinterpret_cast<const f32x4*>(xp + 4);
        v[0] = pack2(f0[0], f0[1]); v[1] = pack2(f0[2], f0[3]);
        v[2] = pack2(f1[0], f1[1]); v[3] = pack2(f1[2], f1[3]);
      }
      int off = (r << 8) + (((kc << 1)) ^ ((r & 7) << 4));
      *reinterpret_cast<i32x4*>(&smem[off]) = v;
    }
#pragma unroll
    for (int i = 0; i < 2; ++i) {
      int c = tid + (i << 8);
      int n = c >> 4, kc = (c & 15) << 3;
      i32x4 v = *reinterpret_cast<const i32x4*>(B2t + (size_t)(n2 + n) * KK + kbase + kc);
      int off = 8192 + (n << 8) + (((kc << 1)) ^ ((n & 7) << 4));
      *reinterpret_cast<i32x4*>(&smem[off]) = v;
    }
    __syncthreads();
#pragma unroll
    for (int ks = 0; ks < 4; ++ks) {
      int kbyte = ks * 64 + l4 * 16;
      int ra = wm * 16 + l15;
      short8 a = *reinterpret_cast<short8*>(&smem[(ra << 8) + (kbyte ^ ((ra & 7) << 4))]);
      int nb = wn * 16 + l15;
      short8 b0 = *reinterpret_cast<short8*>(&smem[8192 + (nb << 8) + (kbyte ^ ((nb & 7) << 4))]);
      acc = __builtin_amdgcn_mfma_f32_16x16x32_bf16(a, b0, acc, 0, 0, 0);
    }
    __syncthreads();
  }
  int mrow = m0 + wm * 16 + l4 * 4;
  int c = n2 + wn * 16 + l15;
#pragma unroll
  for (int j = 0; j < 4; ++j) {
    int m = mrow + j;
    size_t idx = (size_t)m * NH + c;
    float hc = tanhf_(acc[j] + bb[c]);
    float zv = zfb[idx];
    float hn = (1.f - zv) * hf[idx] + zv * hc;
    hf[idx] = hn;
    hb[idx] = f2bf(hn);
    if (t == NT - 1) out[idx] = hn;
  }
}

// ===========================================================================
extern "C" void kernel_launch(void* const* d_in, const int* in_sizes, int n_in,
                              void* d_out, int out_size, void* d_ws, size_t ws_size,
                              hipStream_t stream) {
  const float* x  = (const float*)d_in[0];
  const float* W  = (const float*)d_in[1];
  const float* U  = (const float*)d_in[2];
  const float* Wz = (const float*)d_in[3];
  const float* Uz = (const float*)d_in[4];
  const float* Wr = (const float*)d_in[5];
  const float* Ur = (const float*)d_in[6];
  const float* bb = (const float*)d_in[7];
  const float* bz = (const float*)d_in[8];
  const float* br = (const float*)d_in[9];
  float* out = (float*)d_out;
  char* ws = (char*)d_ws;

  ushort_t* Bu1   = (ushort_t*)(ws);                  //  4,194,304
  ushort_t* Bu2   = (ushort_t*)(ws + 4194304);        //  2,097,152
  ushort_t* Bx    = (ushort_t*)(ws + 6291456);        //  3,145,728
  ushort_t* hb    = (ushort_t*)(ws + 9437184);        //    524,288
  ushort_t* rhb   = (ushort_t*)(ws + 9961472);        //    524,288
  float*    hf    = (float*)   (ws + 10485760);       //  1,048,576
  float*    zfb   = (float*)   (ws + 11534336);       //  1,048,576
  ushort_t* Gx    = (ushort_t*)(ws + 12587008);       // 805,306,368 -> 817,893,376

  const bool fast = (ws_size >= (size_t)817893376ULL);

  if (fast) {
    (void)hipFuncSetAttribute(reinterpret_cast<const void*>(&p1k2),
                              hipFuncAttributeMaxDynamicSharedMemorySize, 73728);
    hipLaunchKernelGGL(repackT, dim3(16, 16), dim3(256), 0, stream, Uz, Bu1, NH);
    hipLaunchKernelGGL(repackT, dim3(16, 16), dim3(256), 0, stream, Ur, Bu1 + (size_t)NH * NH, NH);
    hipLaunchKernelGGL(repackT, dim3(16, 16), dim3(256), 0, stream, U,  Bu2, NH);
    hipLaunchKernelGGL(repackT, dim3(8, 16),  dim3(256), 0, stream, Wz, Bx, ND);
    hipLaunchKernelGGL(repackT, dim3(8, 16),  dim3(256), 0, stream, Wr, Bx + (size_t)NH * ND, ND);
    hipLaunchKernelGGL(repackT, dim3(8, 16),  dim3(256), 0, stream, W,  Bx + (size_t)2 * NH * ND, ND);
    hipLaunchKernelGGL(init_state, dim3(1024), dim3(256), 0, stream, hb, hf);
    hipLaunchKernelGGL(gxgemm, dim3(2048, 48), dim3(256), 0, stream, x, Bx, bz, br, bb, Gx);
    for (int t = 0; t < NT; ++t) {
      hipLaunchKernelGGL(p1k2, dim3(256), dim3(512), 73728, stream,
                         Bu1, hb, rhb, hf, zfb, Gx, t);
      hipLaunchKernelGGL(p2k2, dim3(256), dim3(512), 0, stream,
                         Bu2, rhb, hb, hf, zfb, Gx, out, t);
    }
  } else {
    // fallback: proven round-2 per-step path (K=1536, biases in-loop)
    ushort_t* B1t  = (ushort_t*)(ws);
    ushort_t* B2t  = (ushort_t*)(ws + 6291456);
    ushort_t* hb2  = (ushort_t*)(ws + 9437184);
    ushort_t* rhb2 = (ushort_t*)(ws + 9961472);
    float*    hf2  = (float*)   (ws + 10485760);
    float*    zfb2 = (float*)   (ws + 11534336);
    hipLaunchKernelGGL(repack_weights, dim3(24, 32, 2), dim3(256), 0, stream,
                       U, W, Uz, Wz, Ur, Wr, B1t, B2t);
    hipLaunchKernelGGL(init_state, dim3(1024), dim3(256), 0, stream, hb2, hf2);
    for (int t = 0; t < NT; ++t) {
      hipLaunchKernelGGL(gru_phase1, dim3(256), dim3(256), 0, stream,
                         x, B1t, hb2, rhb2, hf2, zfb2, bz, br, t);
      hipLaunchKernelGGL(gru_phase2, dim3(256), dim3(256), 0, stream,
                         x, B2t, hb2, rhb2, hf2, zfb2, bb, out, t);
    }
  }
}

// Round 11
// 8373.842 us; speedup vs baseline: 4.0699x; 1.0531x over previous
//
#include <hip/hip_runtime.h>

typedef unsigned short ushort_t;
typedef __attribute__((ext_vector_type(8))) short short8;
typedef __attribute__((ext_vector_type(4))) float f32x4;
typedef __attribute__((ext_vector_type(4))) int i32x4;

#define NB   256     // batch
#define NT   512     // timesteps
#define ND   512     // input dim
#define NH   1024    // hidden dim
#define KK   1536    // NH + ND (fallback path concat K)
#define BK   128

__device__ __forceinline__ ushort_t f2bf(float f) {
  union { float f; unsigned u; } v; v.f = f;
  unsigned u = v.u;
  return (ushort_t)((u + 0x7FFFu + ((u >> 16) & 1u)) >> 16);
}
__device__ __forceinline__ int pack2(float a, float b) {
  return (int)(((unsigned)f2bf(b) << 16) | (unsigned)f2bf(a));
}
__device__ __forceinline__ float bf2f(ushort_t h) {
  union { unsigned u; float f; } v; v.u = ((unsigned)h) << 16; return v.f;
}
__device__ __forceinline__ float sigmoidf_(float x) {
  return 1.f / (1.f + __expf(-x));
}
__device__ __forceinline__ float tanhf_(float x) {
  return 1.f - 2.f / (__expf(2.f * x) + 1.f);
}

// ===========================================================================
// Transpose-repack (verified r6-r10): src f32 [K][1024] -> dst bf16 [1024][K].
// ===========================================================================
__global__ void repackT(const float* __restrict__ src, ushort_t* __restrict__ dst,
                        int K) {
  __shared__ float tile[64][65];
  const int k0 = blockIdx.x * 64, n0 = blockIdx.y * 64;
  const int tid = threadIdx.x;
  for (int i = 0; i < 16; ++i) {
    int e = tid + i * 256;
    int r = e >> 6, c = e & 63;
    tile[r][c] = src[(size_t)(k0 + r) * 1024 + n0 + c];
  }
  __syncthreads();
  for (int i = 0; i < 2; ++i) {
    int cch = tid + i * 256;
    int nl = cch >> 3, kc = (cch & 7) * 8;
    ushort_t tmp[8];
#pragma unroll
    for (int j = 0; j < 8; ++j) tmp[j] = f2bf(tile[kc + j][nl]);
    *reinterpret_cast<i32x4*>(dst + (size_t)(n0 + nl) * K + k0 + kc) =
        *reinterpret_cast<i32x4*>(tmp);
  }
}

__global__ void init_state(ushort_t* __restrict__ hb, float* __restrict__ hf) {
  int i = blockIdx.x * 256 + threadIdx.x;
  if (i < NB * NH) { hb[i] = 0; hf[i] = 0.f; }
}

// ===========================================================================
// Gx precompute (verified r6-r10): Gx[t*256+b][j], j: 0..1023=z, 1024..2047=r,
// 2048..3071=cand. Bx bf16 [3072][512] n-major.
// ===========================================================================
__global__ void __launch_bounds__(256)
gxgemm(const float* __restrict__ x, const ushort_t* __restrict__ Bx,
       const float* __restrict__ bz, const float* __restrict__ br,
       const float* __restrict__ bb, ushort_t* __restrict__ Gx) {
  __shared__ __align__(16) char smem[32768];
  const int tid  = threadIdx.x;
  const int m0   = blockIdx.x * 64;
  const int n0   = blockIdx.y * 64;
  const int lane = tid & 63;
  const int w    = tid >> 6;
  const int wm   = w >> 1, wn = w & 1;
  const int l15  = lane & 15, l4 = lane >> 4;

  f32x4 acc[2][2];
#pragma unroll
  for (int i = 0; i < 2; ++i)
#pragma unroll
    for (int j = 0; j < 2; ++j) acc[i][j] = (f32x4){0.f, 0.f, 0.f, 0.f};

  for (int kb = 0; kb < 4; ++kb) {
    const int kbase = kb * BK;
#pragma unroll
    for (int i = 0; i < 4; ++i) {
      int c = tid + (i << 8);
      int r = c >> 4, kc = (c & 15) << 3;
      int m = m0 + r;
      int tt = m >> 8, b = m & 255;
      const float* xp = x + ((size_t)b * NT + tt) * ND + kbase + kc;
      f32x4 f0 = *reinterpret_cast<const f32x4*>(xp);
      f32x4 f1 = *reinterpret_cast<const f32x4*>(xp + 4);
      i32x4 v;
      v[0] = pack2(f0[0], f0[1]); v[1] = pack2(f0[2], f0[3]);
      v[2] = pack2(f1[0], f1[1]); v[3] = pack2(f1[2], f1[3]);
      int off = (r << 8) + (((kc << 1)) ^ ((r & 7) << 4));
      *reinterpret_cast<i32x4*>(&smem[off]) = v;
    }
#pragma unroll
    for (int i = 0; i < 4; ++i) {
      int c = tid + (i << 8);
      int n = c >> 4, kc = (c & 15) << 3;
      i32x4 v = *reinterpret_cast<const i32x4*>(Bx + (size_t)(n0 + n) * 512 + kbase + kc);
      int off = 16384 + (n << 8) + (((kc << 1)) ^ ((n & 7) << 4));
      *reinterpret_cast<i32x4*>(&smem[off]) = v;
    }
    __syncthreads();
#pragma unroll
    for (int ks = 0; ks < 4; ++ks) {
      int kbyte = ks * 64 + l4 * 16;
      short8 a[2], b[2];
#pragma unroll
      for (int i = 0; i < 2; ++i) {
        int ra = wm * 32 + i * 16 + l15;
        a[i] = *reinterpret_cast<short8*>(&smem[(ra << 8) + (kbyte ^ ((ra & 7) << 4))]);
        int nb = wn * 32 + i * 16 + l15;
        b[i] = *reinterpret_cast<short8*>(&smem[16384 + (nb << 8) + (kbyte ^ ((nb & 7) << 4))]);
      }
#pragma unroll
      for (int i = 0; i < 2; ++i)
#pragma unroll
        for (int j = 0; j < 2; ++j)
          acc[i][j] = __builtin_amdgcn_mfma_f32_16x16x32_bf16(a[i], b[j], acc[i][j], 0, 0, 0);
    }
    __syncthreads();
  }
#pragma unroll
  for (int i = 0; i < 2; ++i)
#pragma unroll
    for (int j = 0; j < 2; ++j) {
      int col = n0 + wn * 32 + j * 16 + l15;
      float bias = (col < NH) ? bz[col] : (col < 2 * NH ? br[col - NH] : bb[col - 2 * NH]);
      int mr = m0 + wm * 32 + i * 16 + 4 * l4;
#pragma unroll
      for (int jj = 0; jj < 4; ++jj)
        Gx[(size_t)(mr + jj) * 3072 + col] = f2bf(acc[i][j][jj] + bias);
    }
}

// ===========================================================================
// Phase 1 v3: 512 thr (8 waves), grid 256 = 8 mt(32 rows) x 32 nt(64 cols of
// 2048). XCD-pinned (nt%8 = bid%8). BK=256 -> 4 K-iters, 4 barriers.
// Double-buffered reg-staged LDS: 2 x (16KB A + 32KB B) = 96KB dynamic.
// Wave w = (msub=w>>2, nsub=w&3): one 16x16 tile, K=1024 -> 32 MFMA.
// ===========================================================================
__global__ void __launch_bounds__(512)
p1k3(const ushort_t* __restrict__ Bu1, const ushort_t* __restrict__ hb,
     ushort_t* __restrict__ rhb, const float* __restrict__ hf,
     float* __restrict__ zfb, const ushort_t* __restrict__ Gx, int t) {
  extern __shared__ __align__(16) char dsm[];   // 98304
  const int tid  = threadIdx.x;
  const int bid  = blockIdx.x;
  const int lane = tid & 63;
  const int w    = tid >> 6;
  const int l15  = lane & 15, l4 = lane >> 4;
  const int nt   = bid & 31;
  const int mt   = bid >> 5;
  const int m0   = mt * 32;
  const int n1   = nt * 64;
  const int msub = w >> 2, nsub = w & 3;
  const bool zside = (nt < 16);

  const int akc8 = tid & 31, arow = tid >> 5;   // staging chunk coords
  i32x4 ra[2], rb[4];

#define P1_LOAD(kb_) do {                                                     \
    const ushort_t* hsrc_ = hb + (size_t)m0 * NH + (kb_) * 256 + akc8 * 8;    \
    ra[0] = *reinterpret_cast<const i32x4*>(hsrc_ + (size_t)arow * NH);       \
    ra[1] = *reinterpret_cast<const i32x4*>(hsrc_ + (size_t)(arow + 16) * NH);\
    const ushort_t* bsrc_ = Bu1 + (size_t)n1 * NH + (kb_) * 256 + akc8 * 8;   \
    _Pragma("unroll")                                                         \
    for (int i_ = 0; i_ < 4; ++i_)                                            \
      rb[i_] = *reinterpret_cast<const i32x4*>(                               \
          bsrc_ + (size_t)(arow + 16 * i_) * NH);                             \
  } while (0)

#define P1_WRITE(p_) do {                                                     \
    char* ab_ = dsm + (p_) * 49152;                                           \
    *reinterpret_cast<i32x4*>(ab_ +                                           \
        (((akc8 * 32 + arow) * 16) ^ ((akc8 & 7) << 4))) = ra[0];             \
    *reinterpret_cast<i32x4*>(ab_ +                                           \
        (((akc8 * 32 + arow + 16) * 16) ^ ((akc8 & 7) << 4))) = ra[1];        \
    char* bbase_ = ab_ + 16384;                                               \
    _Pragma("unroll")                                                         \
    for (int i_ = 0; i_ < 4; ++i_)                                            \
      *reinterpret_cast<i32x4*>(bbase_ +                                      \
          (((akc8 * 64 + arow + 16 * i_) * 16) ^ ((akc8 & 7) << 4))) = rb[i_];\
  } while (0)

  P1_LOAD(0);

  // epilogue operand prefetch (after staging issue; completes under K-loop)
  const int mrow = m0 + msub * 16 + 4 * l4;
  const int col1 = n1 + nsub * 16 + l15;
  const size_t gxrow = (size_t)t * NB * 3072;
  float gxe[4], hfe[4];
#pragma unroll
  for (int jj = 0; jj < 4; ++jj) {
    gxe[jj] = bf2f(Gx[gxrow + (size_t)(mrow + jj) * 3072 + col1]);
    if (!zside) hfe[jj] = hf[(size_t)(mrow + jj) * NH + (col1 - NH)];
  }

  f32x4 acc = {0.f, 0.f, 0.f, 0.f};
#pragma unroll
  for (int kb = 0; kb < 4; ++kb) {
    const int p = kb & 1;
    P1_WRITE(p);
    if (kb < 3) P1_LOAD(kb + 1);
    __syncthreads();
    char* base = dsm + p * 49152;
#pragma unroll
    for (int s = 0; s < 8; ++s) {
      int kc8 = s * 4 + l4;
      short8 a = *reinterpret_cast<short8*>(base +
          (((kc8 * 32 + msub * 16 + l15) * 16) ^ ((kc8 & 7) << 4)));
      short8 b = *reinterpret_cast<short8*>(base + 16384 +
          (((kc8 * 64 + nsub * 16 + l15) * 16) ^ ((kc8 & 7) << 4)));
      acc = __builtin_amdgcn_mfma_f32_16x16x32_bf16(a, b, acc, 0, 0, 0);
    }
  }
#undef P1_LOAD
#undef P1_WRITE

  if (zside) {
#pragma unroll
    for (int jj = 0; jj < 4; ++jj)
      zfb[(size_t)(mrow + jj) * NH + col1] = sigmoidf_(acc[jj] + gxe[jj]);
  } else {
    int cc = col1 - NH;
#pragma unroll
    for (int jj = 0; jj < 4; ++jj) {
      float rv = sigmoidf_(acc[jj] + gxe[jj]);
      rhb[(size_t)(mrow + jj) * NH + cc] = f2bf(rv * hfe[jj]);
    }
  }
}

// ===========================================================================
// Phase 2 v3: 512 thr, grid 256 = 8 mt(32 rows) x 32 nt(32 cols of 1024).
// BK=256, 4 iters. Wave (msub=w&1, nsub=(w>>1)&1, kh=w>>2): 16x16 tile over
// K-half -> 16 MFMA; pair reduction (w, w+4) via LDS. 64KB static.
// ===========================================================================
__global__ void __launch_bounds__(512)
p2k3(const ushort_t* __restrict__ Bu2, const ushort_t* __restrict__ rhb,
     ushort_t* __restrict__ hb, float* __restrict__ hf,
     const float* __restrict__ zfb, const ushort_t* __restrict__ Gx,
     float* __restrict__ out, int t) {
  __shared__ __align__(16) char smem[65536];    // 2 x (16KB A + 16KB B)
  const int tid  = threadIdx.x;
  const int bid  = blockIdx.x;
  const int lane = tid & 63;
  const int w    = tid >> 6;
  const int l15  = lane & 15, l4 = lane >> 4;
  const int nt   = bid & 31;
  const int mt   = bid >> 5;
  const int m0   = mt * 32;
  const int n2   = nt * 32;
  const int msub = w & 1, nsub = (w >> 1) & 1, kh = w >> 2;

  const int akc8 = tid & 31, arow = tid >> 5;
  i32x4 ra[2], rb[2];

#define P2_LOAD(kb_) do {                                                     \
    const ushort_t* asrc_ = rhb + (size_t)m0 * NH + (kb_) * 256 + akc8 * 8;   \
    ra[0] = *reinterpret_cast<const i32x4*>(asrc_ + (size_t)arow * NH);       \
    ra[1] = *reinterpret_cast<const i32x4*>(asrc_ + (size_t)(arow + 16) * NH);\
    const ushort_t* bsrc_ = Bu2 + (size_t)n2 * NH + (kb_) * 256 + akc8 * 8;   \
    rb[0] = *reinterpret_cast<const i32x4*>(bsrc_ + (size_t)arow * NH);       \
    rb[1] = *reinterpret_cast<const i32x4*>(bsrc_ + (size_t)(arow + 16) * NH);\
  } while (0)

#define P2_WRITE(p_) do {                                                     \
    char* ab_ = smem + (p_) * 32768;                                          \
    *reinterpret_cast<i32x4*>(ab_ +                                           \
        (((akc8 * 32 + arow) * 16) ^ ((akc8 & 7) << 4))) = ra[0];             \
    *reinterpret_cast<i32x4*>(ab_ +                                           \
        (((akc8 * 32 + arow + 16) * 16) ^ ((akc8 & 7) << 4))) = ra[1];        \
    char* bbase_ = ab_ + 16384;                                               \
    *reinterpret_cast<i32x4*>(bbase_ +                                        \
        (((akc8 * 32 + arow) * 16) ^ ((akc8 & 7) << 4))) = rb[0];             \
    *reinterpret_cast<i32x4*>(bbase_ +                                        \
        (((akc8 * 32 + arow + 16) * 16) ^ ((akc8 & 7) << 4))) = rb[1];        \
  } while (0)

  P2_LOAD(0);

  // epilogue operands (waves 0..3 own output tiles)
  const int mrow = m0 + msub * 16 + 4 * l4;
  const int colw = n2 + ((w >> 1) & 1) * 16 + l15;     // valid for w<4
  const size_t gxrow = (size_t)t * NB * 3072;
  float gxe[4], hfe[4], ze[4];
  if (w < 4) {
#pragma unroll
    for (int jj = 0; jj < 4; ++jj) {
      gxe[jj] = bf2f(Gx[gxrow + (size_t)(mrow + jj) * 3072 + 2048 + colw]);
      hfe[jj] = hf[(size_t)(mrow + jj) * NH + colw];
      ze[jj]  = zfb[(size_t)(mrow + jj) * NH + colw];
    }
  }

  f32x4 acc = {0.f, 0.f, 0.f, 0.f};
#pragma unroll
  for (int kb = 0; kb < 4; ++kb) {
    const int p = kb & 1;
    P2_WRITE(p);
    if (kb < 3) P2_LOAD(kb + 1);
    __syncthreads();
    char* base = smem + p * 32768;
#pragma unroll
    for (int s = 0; s < 4; ++s) {
      int kc8 = kh * 16 + s * 4 + l4;
      short8 a = *reinterpret_cast<short8*>(base +
          (((kc8 * 32 + msub * 16 + l15) * 16) ^ ((kc8 & 7) << 4)));
      short8 b = *reinterpret_cast<short8*>(base + 16384 +
          (((kc8 * 32 + nsub * 16 + l15) * 16) ^ ((kc8 & 7) << 4)));
      acc = __builtin_amdgcn_mfma_f32_16x16x32_bf16(a, b, acc, 0, 0, 0);
    }
  }
#undef P2_LOAD
#undef P2_WRITE

  // pair reduction: wave w+4 -> wave w
  __syncthreads();
  if (w >= 4)
    *reinterpret_cast<f32x4*>(smem + (w - 4) * 1024 + lane * 16) = acc;
  __syncthreads();
  if (w < 4) {
    f32x4 v = acc + *reinterpret_cast<f32x4*>(smem + w * 1024 + lane * 16);
#pragma unroll
    for (int jj = 0; jj < 4; ++jj) {
      size_t idx = (size_t)(mrow + jj) * NH + colw;
      float hc = tanhf_(v[jj] + gxe[jj]);
      float zv = ze[jj];
      float hn = (1.f - zv) * hfe[jj] + zv * hc;
      hf[idx] = hn;
      hb[idx] = f2bf(hn);
      if (t == NT - 1) out[idx] = hn;
    }
  }
}

// ===========================================================================
// ============== FALLBACK (round-2, proven): per-step, K=1536 ===============
// ===========================================================================
__global__ void repack_weights(const float* __restrict__ U,  const float* __restrict__ W,
                               const float* __restrict__ Uz, const float* __restrict__ Wz,
                               const float* __restrict__ Ur, const float* __restrict__ Wr,
                               ushort_t* __restrict__ B1t, ushort_t* __restrict__ B2t) {
  const int kt = blockIdx.x, nt = blockIdx.y, which = blockIdx.z;
  if (which == 1 && nt >= 16) return;
  __shared__ float tile[64][65];
  const int k0 = kt * 64, n0 = nt * 64;
  const int tid = threadIdx.x;
  for (int i = 0; i < 16; ++i) {
    int e = tid + i * 256;
    int r = e >> 6, c = e & 63;
    int k = k0 + r, n = n0 + c;
    int nn = n & 1023;
    const float* src;
    if (which == 0) {
      if (k < NH) src = (n < NH ? Uz : Ur) + (size_t)k * NH + nn;
      else        src = (n < NH ? Wz : Wr) + (size_t)(k - NH) * NH + nn;
    } else {
      if (k < NH) src = U + (size_t)k * NH + nn;
      else        src = W + (size_t)(k - NH) * NH + nn;
    }
    tile[r][c] = *src;
  }
  __syncthreads();
  ushort_t* dst = (which == 0) ? B1t : B2t;
  for (int i = 0; i < 2; ++i) {
    int cch = tid + i * 256;
    int nl = cch >> 3, kc = (cch & 7) * 8;
    ushort_t tmp[8];
#pragma unroll
    for (int j = 0; j < 8; ++j) tmp[j] = f2bf(tile[kc + j][nl]);
    *reinterpret_cast<i32x4*>(dst + (size_t)(n0 + nl) * KK + k0 + kc) =
        *reinterpret_cast<i32x4*>(tmp);
  }
}

__global__ void __launch_bounds__(256)
gru_phase1(const float* __restrict__ x, const ushort_t* __restrict__ B1t,
           const ushort_t* __restrict__ hb, ushort_t* __restrict__ rhb,
           const float* __restrict__ hf, float* __restrict__ zfb,
           const float* __restrict__ bz, const float* __restrict__ br, int t) {
  __shared__ __align__(16) char smem[24576];
  const int tid  = threadIdx.x;
  const int bid  = blockIdx.x;
  const int lane = tid & 63;
  const int w    = tid >> 6;
  const int wm   = w >> 1, wn = w & 1;
  const int m0   = (bid >> 5) * 32;
  const int n1   = (bid & 31) * 64;
  const int l15  = lane & 15, l4 = lane >> 4;

  f32x4 acc0 = {0.f, 0.f, 0.f, 0.f}, acc1 = {0.f, 0.f, 0.f, 0.f};
  for (int kb = 0; kb < KK / BK; ++kb) {
    const int kbase = kb * BK;
#pragma unroll
    for (int i = 0; i < 2; ++i) {
      int c = tid + (i << 8);
      int r = c >> 4, kc = (c & 15) << 3;
      int m = m0 + r, k = kbase + kc;
      i32x4 v;
      if (k < NH) {
        v = *reinterpret_cast<const i32x4*>(hb + (size_t)m * NH + k);
      } else {
        const float* xp = x + (size_t)m * (NT * ND) + (size_t)t * ND + (k - NH);
        f32x4 f0 = *reinterpret_cast<const f32x4*>(xp);
        f32x4 f1 = *reinterpret_cast<const f32x4*>(xp + 4);
        v[0] = pack2(f0[0], f0[1]); v[1] = pack2(f0[2], f0[3]);
        v[2] = pack2(f1[0], f1[1]); v[3] = pack2(f1[2], f1[3]);
      }
      int off = (r << 8) + (((kc << 1)) ^ ((r & 7) << 4));
      *reinterpret_cast<i32x4*>(&smem[off]) = v;
    }
#pragma unroll
    for (int i = 0; i < 4; ++i) {
      int c = tid + (i << 8);
      int n = c >> 4, kc = (c & 15) << 3;
      i32x4 v = *reinterpret_cast<const i32x4*>(B1t + (size_t)(n1 + n) * KK + kbase + kc);
      int off = 8192 + (n << 8) + (((kc << 1)) ^ ((n & 7) << 4));
      *reinterpret_cast<i32x4*>(&smem[off]) = v;
    }
    __syncthreads();
#pragma unroll
    for (int ks = 0; ks < 4; ++ks) {
      int kbyte = ks * 64 + l4 * 16;
      int ra = wm * 16 + l15;
      short8 a = *reinterpret_cast<short8*>(&smem[(ra << 8) + (kbyte ^ ((ra & 7) << 4))]);
      int nb0 = wn * 32 + l15;
      short8 b0 = *reinterpret_cast<short8*>(&smem[8192 + (nb0 << 8) + (kbyte ^ ((nb0 & 7) << 4))]);
      int nb1 = nb0 + 16;
      short8 b1 = *reinterpret_cast<short8*>(&smem[8192 + (nb1 << 8) + (kbyte ^ ((nb1 & 7) << 4))]);
      acc0 = __builtin_amdgcn_mfma_f32_16x16x32_bf16(a, b0, acc0, 0, 0, 0);
      acc1 = __builtin_amdgcn_mfma_f32_16x16x32_bf16(a, b1, acc1, 0, 0, 0);
    }
    __syncthreads();
  }
  int mrow = m0 + wm * 16 + l4 * 4;
#pragma unroll
  for (int f = 0; f < 2; ++f) {
    f32x4 av = f ? acc1 : acc0;
    int c = n1 + wn * 32 + f * 16 + l15;
#pragma unroll
    for (int j = 0; j < 4; ++j) {
      int m = mrow + j;
      float v = av[j];
      if (c < NH) {
        zfb[(size_t)m * NH + c] = sigmoidf_(v + bz[c]);
      } else {
        int cc = c - NH;
        float rv = sigmoidf_(v + br[cc]);
        rhb[(size_t)m * NH + cc] = f2bf(rv * hf[(size_t)m * NH + cc]);
      }
    }
  }
}

__global__ void __launch_bounds__(256)
gru_phase2(const float* __restrict__ x, const ushort_t* __restrict__ B2t,
           ushort_t* __restrict__ hb, const ushort_t* __restrict__ rhb,
           float* __restrict__ hf, const float* __restrict__ zfb,
           const float* __restrict__ bb, float* __restrict__ out, int t) {
  __shared__ __align__(16) char smem[16384];
  const int tid  = threadIdx.x;
  const int bid  = blockIdx.x;
  const int lane = tid & 63;
  const int w    = tid >> 6;
  const int wm   = w >> 1, wn = w & 1;
  const int m0   = (bid >> 5) * 32;
  const int n2   = (bid & 31) * 32;
  const int l15  = lane & 15, l4 = lane >> 4;

  f32x4 acc = {0.f, 0.f, 0.f, 0.f};
  for (int kb = 0; kb < KK / BK; ++kb) {
    const int kbase = kb * BK;
#pragma unroll
    for (int i = 0; i < 2; ++i) {
      int c = tid + (i << 8);
      int r = c >> 4, kc = (c & 15) << 3;
      int m = m0 + r, k = kbase + kc;
      i32x4 v;
      if (k < NH) {
        v = *reinterpret_cast<const i32x4*>(rhb + (size_t)m * NH + k);
      } else {
        const float* xp = x + (size_t)m * (NT * ND) + (size_t)t * ND + (k - NH);
        f32x4 f0 = *reinterpret_cast<const f32x4*>(xp);
        f32x4 f1 = *reinterpret_cast<const f32x4*>(xp + 4);
        v[0] = pack2(f0[0], f0[1]); v[1] = pack2(f0[2], f0[3]);
        v[2] = pack2(f1[1], f1[1]); v[3] = pack2(f1[2], f1[3]);
      }
      int off = (r << 8) + (((kc << 1)) ^ ((r & 7) << 4));
      *reinterpret_cast<i32x4*>(&smem[off]) = v;
    }
#pragma unroll
    for (int i = 0; i < 2; ++i) {
      int c = tid + (i << 8);
      int n = c >> 4, kc = (c & 15) << 3;
      i32x4 v = *reinterpret_cast<const i32x4*>(B2t + (size_t)(n2 + n) * KK + kbase + kc);
      int off = 8192 + (n << 8) + (((kc << 1)) ^ ((n & 7) << 4));
      *reinterpret_cast<i32x4*>(&smem[off]) = v;
    }
    __syncthreads();
#pragma unroll
    for (int ks = 0; ks < 4; ++ks) {
      int kbyte = ks * 64 + l4 * 16;
      int ra = wm * 16 + l15;
      short8 a = *reinterpret_cast<short8*>(&smem[(ra << 8) + (kbyte ^ ((ra & 7) << 4))]);
      int nb = wn * 16 + l15;
      short8 b0 = *reinterpret_cast<short8*>(&smem[8192 + (nb << 8) + (kbyte ^ ((nb & 7) << 4))]);
      acc = __builtin_amdgcn_mfma_f32_16x16x32_bf16(a, b0, acc, 0, 0, 0);
    }
    __syncthreads();
  }
  int mrow = m0 + wm * 16 + l4 * 4;
  int c = n2 + wn * 16 + l15;
#pragma unroll
  for (int j = 0; j < 4; ++j) {
    int m = mrow + j;
    size_t idx = (size_t)m * NH + c;
    float hc = tanhf_(acc[j] + bb[c]);
    float zv = zfb[idx];
    float hn = (1.f - zv) * hf[idx] + zv * hc;
    hf[idx] = hn;
    hb[idx] = f2bf(hn);
    if (t == NT - 1) out[idx] = hn;
  }
}

// ===========================================================================
extern "C" void kernel_launch(void* const* d_in, const int* in_sizes, int n_in,
                              void* d_out, int out_size, void* d_ws, size_t ws_size,
                              hipStream_t stream) {
  const float* x  = (const float*)d_in[0];
  const float* W  = (const float*)d_in[1];
  const float* U  = (const float*)d_in[2];
  const float* Wz = (const float*)d_in[3];
  const float* Uz = (const float*)d_in[4];
  const float* Wr = (const float*)d_in[5];
  const float* Ur = (const float*)d_in[6];
  const float* bb = (const float*)d_in[7];
  const float* bz = (const float*)d_in[8];
  const float* br = (const float*)d_in[9];
  float* out = (float*)d_out;
  char* ws = (char*)d_ws;

  ushort_t* Bu1   = (ushort_t*)(ws);                  //  4,194,304
  ushort_t* Bu2   = (ushort_t*)(ws + 4194304);        //  2,097,152
  ushort_t* Bx    = (ushort_t*)(ws + 6291456);        //  3,145,728
  ushort_t* hb    = (ushort_t*)(ws + 9437184);        //    524,288
  ushort_t* rhb   = (ushort_t*)(ws + 9961472);        //    524,288
  float*    hf    = (float*)   (ws + 10485760);       //  1,048,576
  float*    zfb   = (float*)   (ws + 11534336);       //  1,048,576
  ushort_t* Gx    = (ushort_t*)(ws + 12587008);       // 805,306,368 -> 817,893,376

  const bool fast = (ws_size >= (size_t)817893376ULL);

  if (fast) {
    (void)hipFuncSetAttribute(reinterpret_cast<const void*>(&p1k3),
                              hipFuncAttributeMaxDynamicSharedMemorySize, 98304);
    hipLaunchKernelGGL(repackT, dim3(16, 16), dim3(256), 0, stream, Uz, Bu1, NH);
    hipLaunchKernelGGL(repackT, dim3(16, 16), dim3(256), 0, stream, Ur, Bu1 + (size_t)NH * NH, NH);
    hipLaunchKernelGGL(repackT, dim3(16, 16), dim3(256), 0, stream, U,  Bu2, NH);
    hipLaunchKernelGGL(repackT, dim3(8, 16),  dim3(256), 0, stream, Wz, Bx, ND);
    hipLaunchKernelGGL(repackT, dim3(8, 16),  dim3(256), 0, stream, Wr, Bx + (size_t)NH * ND, ND);
    hipLaunchKernelGGL(repackT, dim3(8, 16),  dim3(256), 0, stream, W,  Bx + (size_t)2 * NH * ND, ND);
    hipLaunchKernelGGL(init_state, dim3(1024), dim3(256), 0, stream, hb, hf);
    hipLaunchKernelGGL(gxgemm, dim3(2048, 48), dim3(256), 0, stream, x, Bx, bz, br, bb, Gx);
    for (int t = 0; t < NT; ++t) {
      hipLaunchKernelGGL(p1k3, dim3(256), dim3(512), 98304, stream,
                         Bu1, hb, rhb, hf, zfb, Gx, t);
      hipLaunchKernelGGL(p2k3, dim3(256), dim3(512), 0, stream,
                         Bu2, rhb, hb, hf, zfb, Gx, out, t);
    }
  } else {
    // fallback: proven round-2 per-step path (K=1536, biases in-loop)
    ushort_t* B1t  = (ushort_t*)(ws);
    ushort_t* B2t  = (ushort_t*)(ws + 6291456);
    ushort_t* hb2  = (ushort_t*)(ws + 9437184);
    ushort_t* rhb2 = (ushort_t*)(ws + 9961472);
    float*    hf2  = (float*)   (ws + 10485760);
    float*    zfb2 = (float*)   (ws + 11534336);
    hipLaunchKernelGGL(repack_weights, dim3(24, 32, 2), dim3(256), 0, stream,
                       U, W, Uz, Wz, Ur, Wr, B1t, B2t);
    hipLaunchKernelGGL(init_state, dim3(1024), dim3(256), 0, stream, hb2, hf2);
    for (int t = 0; t < NT; ++t) {
      hipLaunchKernelGGL(gru_phase1, dim3(256), dim3(256), 0, stream,
                         x, B1t, hb2, rhb2, hf2, zfb2, bz, br, t);
      hipLaunchKernelGGL(gru_phase2, dim3(256), dim3(256), 0, stream,
                         x, B2t, hb2, rhb2, hf2, zfb2, bb, out, t);
    }
  }
}

// Round 12
// 7830.691 us; speedup vs baseline: 4.3522x; 1.0694x over previous
//
#include <hip/hip_runtime.h>

typedef unsigned short ushort_t;
typedef __attribute__((ext_vector_type(8))) short short8;
typedef __attribute__((ext_vector_type(4))) float f32x4;
typedef __attribute__((ext_vector_type(4))) int i32x4;

#define NB   256     // batch
#define NT   512     // timesteps
#define ND   512     // input dim
#define NH   1024    // hidden dim
#define KK   1536    // NH + ND (fallback path concat K)
#define BK   128

__device__ __forceinline__ ushort_t f2bf(float f) {
  union { float f; unsigned u; } v; v.f = f;
  unsigned u = v.u;
  return (ushort_t)((u + 0x7FFFu + ((u >> 16) & 1u)) >> 16);
}
__device__ __forceinline__ int pack2(float a, float b) {
  return (int)(((unsigned)f2bf(b) << 16) | (unsigned)f2bf(a));
}
__device__ __forceinline__ float bf2f(ushort_t h) {
  union { unsigned u; float f; } v; v.u = ((unsigned)h) << 16; return v.f;
}
__device__ __forceinline__ float sigmoidf_(float x) {
  return 1.f / (1.f + __expf(-x));
}
__device__ __forceinline__ float tanhf_(float x) {
  return 1.f - 2.f / (__expf(2.f * x) + 1.f);
}

// ===========================================================================
// Transpose-repack (verified r6-r11): src f32 [K][1024] -> dst bf16 [1024][K].
// ===========================================================================
__global__ void repackT(const float* __restrict__ src, ushort_t* __restrict__ dst,
                        int K) {
  __shared__ float tile[64][65];
  const int k0 = blockIdx.x * 64, n0 = blockIdx.y * 64;
  const int tid = threadIdx.x;
  for (int i = 0; i < 16; ++i) {
    int e = tid + i * 256;
    int r = e >> 6, c = e & 63;
    tile[r][c] = src[(size_t)(k0 + r) * 1024 + n0 + c];
  }
  __syncthreads();
  for (int i = 0; i < 2; ++i) {
    int cch = tid + i * 256;
    int nl = cch >> 3, kc = (cch & 7) * 8;
    ushort_t tmp[8];
#pragma unroll
    for (int j = 0; j < 8; ++j) tmp[j] = f2bf(tile[kc + j][nl]);
    *reinterpret_cast<i32x4*>(dst + (size_t)(n0 + nl) * K + k0 + kc) =
        *reinterpret_cast<i32x4*>(tmp);
  }
}

__global__ void init_state(ushort_t* __restrict__ hb, float* __restrict__ hf) {
  int i = blockIdx.x * 256 + threadIdx.x;
  if (i < NB * NH) { hb[i] = 0; hf[i] = 0.f; }
}

// ===========================================================================
// Gx precompute v2: 128x128 tile, BK=64, 4 waves x (4x4 acc), double-buffered.
// Gx[t*256+b][j], j: 0..1023=z, 1024..2047=r, 2048..3071=cand.
// Bx bf16 [3072][512] n-major. grid (1024, 24), 256 thr.
// LDS chunk layout: granule(row,kc8) = (row*8+kc8) ^ (row&7) -> write AND
// MFMA-read both bank-conflict-free (bijective within 64-granule windows).
// ===========================================================================
#define GOFF(row_, kc8_) (((((row_) * 8 + (kc8_)) << 4)) ^ (((row_) & 7) << 4))

__global__ void __launch_bounds__(256)
gxgemm2(const float* __restrict__ x, const ushort_t* __restrict__ Bx,
        const float* __restrict__ bz, const float* __restrict__ br,
        const float* __restrict__ bb, ushort_t* __restrict__ Gx) {
  __shared__ __align__(16) char smem[65536];   // 2 x (A 16KB + B 16KB)
  const int tid  = threadIdx.x;
  const int m0   = blockIdx.x * 128;
  const int n0   = blockIdx.y * 128;
  const int lane = tid & 63;
  const int w    = tid >> 6;
  const int wm   = w >> 1, wn = w & 1;
  const int l15  = lane & 15, l4 = lane >> 4;
  const int tt   = m0 >> 8;                    // timestep (constant per tile)
  const int b0   = m0 & 255;                   // batch base

  // staging regs (chunk c = tid + i*256: row=c>>3, kc8=c&7)
  f32x4 rxa[4][2];   // A source f32 (packed at write)
  i32x4 rxb[4];      // B chunks

#define GX_LOAD(kb_) do {                                                     \
    int kbase_ = (kb_) * 64;                                                  \
    _Pragma("unroll")                                                         \
    for (int i_ = 0; i_ < 4; ++i_) {                                          \
      int c_ = tid + i_ * 256;                                                \
      int row_ = c_ >> 3, kc8_ = c_ & 7;                                      \
      const float* xp_ = x + ((size_t)(b0 + row_) * NT + tt) * ND             \
                          + kbase_ + kc8_ * 8;                                \
      rxa[i_][0] = *reinterpret_cast<const f32x4*>(xp_);                      \
      rxa[i_][1] = *reinterpret_cast<const f32x4*>(xp_ + 4);                  \
      rxb[i_] = *reinterpret_cast<const i32x4*>(                              \
          Bx + (size_t)(n0 + row_) * 512 + kbase_ + kc8_ * 8);                \
    }                                                                         \
  } while (0)

#define GX_WRITE(p_) do {                                                     \
    char* ab_ = smem + (p_) * 32768;                                          \
    _Pragma("unroll")                                                         \
    for (int i_ = 0; i_ < 4; ++i_) {                                          \
      int c_ = tid + i_ * 256;                                                \
      int row_ = c_ >> 3, kc8_ = c_ & 7;                                      \
      i32x4 v_;                                                               \
      v_[0] = pack2(rxa[i_][0][0], rxa[i_][0][1]);                            \
      v_[1] = pack2(rxa[i_][0][2], rxa[i_][0][3]);                            \
      v_[2] = pack2(rxa[i_][1][0], rxa[i_][1][1]);                            \
      v_[3] = pack2(rxa[i_][1][2], rxa[i_][1][3]);                            \
      *reinterpret_cast<i32x4*>(ab_ + GOFF(row_, kc8_)) = v_;                 \
      *reinterpret_cast<i32x4*>(ab_ + 16384 + GOFF(row_, kc8_)) = rxb[i_];    \
    }                                                                         \
  } while (0)

  f32x4 acc[4][4];
#pragma unroll
  for (int i = 0; i < 4; ++i)
#pragma unroll
    for (int j = 0; j < 4; ++j) acc[i][j] = (f32x4){0.f, 0.f, 0.f, 0.f};

  GX_LOAD(0);
#pragma unroll
  for (int kb = 0; kb < 8; ++kb) {
    const int p = kb & 1;
    GX_WRITE(p);
    if (kb < 7) GX_LOAD(kb + 1);
    __syncthreads();
    char* base = smem + p * 32768;
#pragma unroll
    for (int ks = 0; ks < 2; ++ks) {
      int kc8 = ks * 4 + l4;
      short8 a[4], bfr[4];
#pragma unroll
      for (int i = 0; i < 4; ++i) {
        int row = wm * 64 + i * 16 + l15;
        a[i] = *reinterpret_cast<short8*>(base + GOFF(row, kc8));
        int col = wn * 64 + i * 16 + l15;
        bfr[i] = *reinterpret_cast<short8*>(base + 16384 + GOFF(col, kc8));
      }
#pragma unroll
      for (int i = 0; i < 4; ++i)
#pragma unroll
        for (int j = 0; j < 4; ++j)
          acc[i][j] = __builtin_amdgcn_mfma_f32_16x16x32_bf16(a[i], bfr[j], acc[i][j], 0, 0, 0);
    }
  }
#undef GX_LOAD
#undef GX_WRITE

  // epilogue: + bias -> bf16
#pragma unroll
  for (int j = 0; j < 4; ++j) {
    int col = n0 + wn * 64 + j * 16 + l15;
    float bias = (col < NH) ? bz[col] : (col < 2 * NH ? br[col - NH] : bb[col - 2 * NH]);
#pragma unroll
    for (int i = 0; i < 4; ++i) {
      int mr = m0 + wm * 64 + i * 16 + 4 * l4;
#pragma unroll
      for (int jj = 0; jj < 4; ++jj)
        Gx[(size_t)(mr + jj) * 3072 + col] = f2bf(acc[i][j][jj] + bias);
    }
  }
}

// ===========================================================================
// Phase 1 v4 (r11 geometry + depth-2 prefetch): 512 thr, grid 256 =
// 8 mt(32 rows) x 32 nt(64 cols of 2048). XCD-pinned (nt%8 = bid%8).
// BK=256 -> 4 K-iters, 4 barriers. LDS 2 x (16KB A + 32KB B) = 96KB dynamic.
// Wave w = (msub=w>>2, nsub=w&3): one 16x16 tile, K=1024 -> 32 MFMA.
// ===========================================================================
__global__ void __launch_bounds__(512)
p1k4(const ushort_t* __restrict__ Bu1, const ushort_t* __restrict__ hb,
     ushort_t* __restrict__ rhb, const float* __restrict__ hf,
     float* __restrict__ zfb, const ushort_t* __restrict__ Gx, int t) {
  extern __shared__ __align__(16) char dsm[];   // 98304
  const int tid  = threadIdx.x;
  const int bid  = blockIdx.x;
  const int lane = tid & 63;
  const int w    = tid >> 6;
  const int l15  = lane & 15, l4 = lane >> 4;
  const int nt   = bid & 31;
  const int mt   = bid >> 5;
  const int m0   = mt * 32;
  const int n1   = nt * 64;
  const int msub = w >> 2, nsub = w & 3;
  const bool zside = (nt < 16);

  const int akc8 = tid & 31, arow = tid >> 5;
  i32x4 raA[2], rbA[4], raB[2], rbB[4];

#define P1_LOAD(RA, RB, kb_) do {                                             \
    const ushort_t* hsrc_ = hb + (size_t)m0 * NH + (kb_) * 256 + akc8 * 8;    \
    RA[0] = *reinterpret_cast<const i32x4*>(hsrc_ + (size_t)arow * NH);       \
    RA[1] = *reinterpret_cast<const i32x4*>(hsrc_ + (size_t)(arow + 16) * NH);\
    const ushort_t* bsrc_ = Bu1 + (size_t)n1 * NH + (kb_) * 256 + akc8 * 8;   \
    _Pragma("unroll")                                                         \
    for (int i_ = 0; i_ < 4; ++i_)                                            \
      RB[i_] = *reinterpret_cast<const i32x4*>(                               \
          bsrc_ + (size_t)(arow + 16 * i_) * NH);                             \
  } while (0)

#define P1_WRITE(p_, RA, RB) do {                                             \
    char* ab_ = dsm + (p_) * 49152;                                           \
    *reinterpret_cast<i32x4*>(ab_ +                                           \
        (((akc8 * 32 + arow) * 16) ^ ((akc8 & 7) << 4))) = RA[0];             \
    *reinterpret_cast<i32x4*>(ab_ +                                           \
        (((akc8 * 32 + arow + 16) * 16) ^ ((akc8 & 7) << 4))) = RA[1];        \
    char* bbase_ = ab_ + 16384;                                               \
    _Pragma("unroll")                                                         \
    for (int i_ = 0; i_ < 4; ++i_)                                            \
      *reinterpret_cast<i32x4*>(bbase_ +                                      \
          (((akc8 * 64 + arow + 16 * i_) * 16) ^ ((akc8 & 7) << 4))) = RB[i_];\
  } while (0)

#define P1_MFMA(p_) do {                                                      \
    char* base_ = dsm + (p_) * 49152;                                         \
    _Pragma("unroll")                                                         \
    for (int s_ = 0; s_ < 8; ++s_) {                                          \
      int kc8_ = s_ * 4 + l4;                                                 \
      short8 a_ = *reinterpret_cast<short8*>(base_ +                          \
          (((kc8_ * 32 + msub * 16 + l15) * 16) ^ ((kc8_ & 7) << 4)));        \
      short8 b_ = *reinterpret_cast<short8*>(base_ + 16384 +                  \
          (((kc8_ * 64 + nsub * 16 + l15) * 16) ^ ((kc8_ & 7) << 4)));        \
      acc = __builtin_amdgcn_mfma_f32_16x16x32_bf16(a_, b_, acc, 0, 0, 0);    \
    }                                                                         \
  } while (0)

  P1_LOAD(raA, rbA, 0);

  // epilogue operand prefetch (completes under K-loop)
  const int mrow = m0 + msub * 16 + 4 * l4;
  const int col1 = n1 + nsub * 16 + l15;
  const size_t gxrow = (size_t)t * NB * 3072;
  float gxe[4], hfe[4];
#pragma unroll
  for (int jj = 0; jj < 4; ++jj) {
    gxe[jj] = bf2f(Gx[gxrow + (size_t)(mrow + jj) * 3072 + col1]);
    if (!zside) hfe[jj] = hf[(size_t)(mrow + jj) * NH + (col1 - NH)];
  }

  P1_LOAD(raB, rbB, 1);

  f32x4 acc = {0.f, 0.f, 0.f, 0.f};
  // kb=0
  P1_WRITE(0, raA, rbA);
  P1_LOAD(raA, rbA, 2);
  __syncthreads();
  P1_MFMA(0);
  // kb=1
  P1_WRITE(1, raB, rbB);
  P1_LOAD(raB, rbB, 3);
  __syncthreads();
  P1_MFMA(1);
  // kb=2
  P1_WRITE(0, raA, rbA);
  __syncthreads();
  P1_MFMA(0);
  // kb=3
  P1_WRITE(1, raB, rbB);
  __syncthreads();
  P1_MFMA(1);
#undef P1_LOAD
#undef P1_WRITE
#undef P1_MFMA

  if (zside) {
#pragma unroll
    for (int jj = 0; jj < 4; ++jj)
      zfb[(size_t)(mrow + jj) * NH + col1] = sigmoidf_(acc[jj] + gxe[jj]);
  } else {
    int cc = col1 - NH;
#pragma unroll
    for (int jj = 0; jj < 4; ++jj) {
      float rv = sigmoidf_(acc[jj] + gxe[jj]);
      rhb[(size_t)(mrow + jj) * NH + cc] = f2bf(rv * hfe[jj]);
    }
  }
}

// ===========================================================================
// Phase 2 v4 (r11 geometry + depth-2 prefetch): 512 thr, grid 256 =
// 8 mt(32 rows) x 32 nt(32 cols of 1024). BK=256, 4 iters.
// Wave (msub=w&1, nsub=(w>>1)&1, kh=w>>2): 16x16 tile over K-half -> 16 MFMA;
// pair reduction (w, w+4) via LDS. 64KB static.
// ===========================================================================
__global__ void __launch_bounds__(512)
p2k4(const ushort_t* __restrict__ Bu2, const ushort_t* __restrict__ rhb,
     ushort_t* __restrict__ hb, float* __restrict__ hf,
     const float* __restrict__ zfb, const ushort_t* __restrict__ Gx,
     float* __restrict__ out, int t) {
  __shared__ __align__(16) char smem[65536];    // 2 x (16KB A + 16KB B)
  const int tid  = threadIdx.x;
  const int bid  = blockIdx.x;
  const int lane = tid & 63;
  const int w    = tid >> 6;
  const int l15  = lane & 15, l4 = lane >> 4;
  const int nt   = bid & 31;
  const int mt   = bid >> 5;
  const int m0   = mt * 32;
  const int n2   = nt * 32;
  const int msub = w & 1, nsub = (w >> 1) & 1, kh = w >> 2;

  const int akc8 = tid & 31, arow = tid >> 5;
  i32x4 raA[2], rbA[2], raB[2], rbB[2];

#define P2_LOAD(RA, RB, kb_) do {                                             \
    const ushort_t* asrc_ = rhb + (size_t)m0 * NH + (kb_) * 256 + akc8 * 8;   \
    RA[0] = *reinterpret_cast<const i32x4*>(asrc_ + (size_t)arow * NH);       \
    RA[1] = *reinterpret_cast<const i32x4*>(asrc_ + (size_t)(arow + 16) * NH);\
    const ushort_t* bsrc_ = Bu2 + (size_t)n2 * NH + (kb_) * 256 + akc8 * 8;   \
    RB[0] = *reinterpret_cast<const i32x4*>(bsrc_ + (size_t)arow * NH);       \
    RB[1] = *reinterpret_cast<const i32x4*>(bsrc_ + (size_t)(arow + 16) * NH);\
  } while (0)

#define P2_WRITE(p_, RA, RB) do {                                             \
    char* ab_ = smem + (p_) * 32768;                                          \
    *reinterpret_cast<i32x4*>(ab_ +                                           \
        (((akc8 * 32 + arow) * 16) ^ ((akc8 & 7) << 4))) = RA[0];             \
    *reinterpret_cast<i32x4*>(ab_ +                                           \
        (((akc8 * 32 + arow + 16) * 16) ^ ((akc8 & 7) << 4))) = RA[1];        \
    char* bbase_ = ab_ + 16384;                                               \
    *reinterpret_cast<i32x4*>(bbase_ +                                        \
        (((akc8 * 32 + arow) * 16) ^ ((akc8 & 7) << 4))) = RB[0];             \
    *reinterpret_cast<i32x4*>(bbase_ +                                        \
        (((akc8 * 32 + arow + 16) * 16) ^ ((akc8 & 7) << 4))) = RB[1];        \
  } while (0)

#define P2_MFMA(p_) do {                                                      \
    char* base_ = smem + (p_) * 32768;                                        \
    _Pragma("unroll")                                                         \
    for (int s_ = 0; s_ < 4; ++s_) {                                          \
      int kc8_ = kh * 16 + s_ * 4 + l4;                                       \
      short8 a_ = *reinterpret_cast<short8*>(base_ +                          \
          (((kc8_ * 32 + msub * 16 + l15) * 16) ^ ((kc8_ & 7) << 4)));        \
      short8 b_ = *reinterpret_cast<short8*>(base_ + 16384 +                  \
          (((kc8_ * 32 + nsub * 16 + l15) * 16) ^ ((kc8_ & 7) << 4)));        \
      acc = __builtin_amdgcn_mfma_f32_16x16x32_bf16(a_, b_, acc, 0, 0, 0);    \
    }                                                                         \
  } while (0)

  P2_LOAD(raA, rbA, 0);

  // epilogue operands (waves 0..3 own output tiles)
  const int mrow = m0 + msub * 16 + 4 * l4;
  const int colw = n2 + ((w >> 1) & 1) * 16 + l15;     // valid for w<4
  const size_t gxrow = (size_t)t * NB * 3072;
  float gxe[4], hfe[4], ze[4];
  if (w < 4) {
#pragma unroll
    for (int jj = 0; jj < 4; ++jj) {
      gxe[jj] = bf2f(Gx[gxrow + (size_t)(mrow + jj) * 3072 + 2048 + colw]);
      hfe[jj] = hf[(size_t)(mrow + jj) * NH + colw];
      ze[jj]  = zfb[(size_t)(mrow + jj) * NH + colw];
    }
  }

  P2_LOAD(raB, rbB, 1);

  f32x4 acc = {0.f, 0.f, 0.f, 0.f};
  // kb=0
  P2_WRITE(0, raA, rbA);
  P2_LOAD(raA, rbA, 2);
  __syncthreads();
  P2_MFMA(0);
  // kb=1
  P2_WRITE(1, raB, rbB);
  P2_LOAD(raB, rbB, 3);
  __syncthreads();
  P2_MFMA(1);
  // kb=2
  P2_WRITE(0, raA, rbA);
  __syncthreads();
  P2_MFMA(0);
  // kb=3
  P2_WRITE(1, raB, rbB);
  __syncthreads();
  P2_MFMA(1);
#undef P2_LOAD
#undef P2_WRITE
#undef P2_MFMA

  // pair reduction: wave w+4 -> wave w
  __syncthreads();
  if (w >= 4)
    *reinterpret_cast<f32x4*>(smem + (w - 4) * 1024 + lane * 16) = acc;
  __syncthreads();
  if (w < 4) {
    f32x4 v = acc + *reinterpret_cast<f32x4*>(smem + w * 1024 + lane * 16);
#pragma unroll
    for (int jj = 0; jj < 4; ++jj) {
      size_t idx = (size_t)(mrow + jj) * NH + colw;
      float hc = tanhf_(v[jj] + gxe[jj]);
      float zv = ze[jj];
      float hn = (1.f - zv) * hfe[jj] + zv * hc;
      hf[idx] = hn;
      hb[idx] = f2bf(hn);
      if (t == NT - 1) out[idx] = hn;
    }
  }
}

// ===========================================================================
// ============== FALLBACK (round-2, proven): per-step, K=1536 ===============
// ===========================================================================
__global__ void repack_weights(const float* __restrict__ U,  const float* __restrict__ W,
                               const float* __restrict__ Uz, const float* __restrict__ Wz,
                               const float* __restrict__ Ur, const float* __restrict__ Wr,
                               ushort_t* __restrict__ B1t, ushort_t* __restrict__ B2t) {
  const int kt = blockIdx.x, nt = blockIdx.y, which = blockIdx.z;
  if (which == 1 && nt >= 16) return;
  __shared__ float tile[64][65];
  const int k0 = kt * 64, n0 = nt * 64;
  const int tid = threadIdx.x;
  for (int i = 0; i < 16; ++i) {
    int e = tid + i * 256;
    int r = e >> 6, c = e & 63;
    int k = k0 + r, n = n0 + c;
    int nn = n & 1023;
    const float* src;
    if (which == 0) {
      if (k < NH) src = (n < NH ? Uz : Ur) + (size_t)k * NH + nn;
      else        src = (n < NH ? Wz : Wr) + (size_t)(k - NH) * NH + nn;
    } else {
      if (k < NH) src = U + (size_t)k * NH + nn;
      else        src = W + (size_t)(k - NH) * NH + nn;
    }
    tile[r][c] = *src;
  }
  __syncthreads();
  ushort_t* dst = (which == 0) ? B1t : B2t;
  for (int i = 0; i < 2; ++i) {
    int cch = tid + i * 256;
    int nl = cch >> 3, kc = (cch & 7) * 8;
    ushort_t tmp[8];
#pragma unroll
    for (int j = 0; j < 8; ++j) tmp[j] = f2bf(tile[kc + j][nl]);
    *reinterpret_cast<i32x4*>(dst + (size_t)(n0 + nl) * KK + k0 + kc) =
        *reinterpret_cast<i32x4*>(tmp);
  }
}

__global__ void __launch_bounds__(256)
gru_phase1(const float* __restrict__ x, const ushort_t* __restrict__ B1t,
           const ushort_t* __restrict__ hb, ushort_t* __restrict__ rhb,
           const float* __restrict__ hf, float* __restrict__ zfb,
           const float* __restrict__ bz, const float* __restrict__ br, int t) {
  __shared__ __align__(16) char smem[24576];
  const int tid  = threadIdx.x;
  const int bid  = blockIdx.x;
  const int lane = tid & 63;
  const int w    = tid >> 6;
  const int wm   = w >> 1, wn = w & 1;
  const int m0   = (bid >> 5) * 32;
  const int n1   = (bid & 31) * 64;
  const int l15  = lane & 15, l4 = lane >> 4;

  f32x4 acc0 = {0.f, 0.f, 0.f, 0.f}, acc1 = {0.f, 0.f, 0.f, 0.f};
  for (int kb = 0; kb < KK / BK; ++kb) {
    const int kbase = kb * BK;
#pragma unroll
    for (int i = 0; i < 2; ++i) {
      int c = tid + (i << 8);
      int r = c >> 4, kc = (c & 15) << 3;
      int m = m0 + r, k = kbase + kc;
      i32x4 v;
      if (k < NH) {
        v = *reinterpret_cast<const i32x4*>(hb + (size_t)m * NH + k);
      } else {
        const float* xp = x + (size_t)m * (NT * ND) + (size_t)t * ND + (k - NH);
        f32x4 f0 = *reinterpret_cast<const f32x4*>(xp);
        f32x4 f1 = *reinterpret_cast<const f32x4*>(xp + 4);
        v[0] = pack2(f0[0], f0[1]); v[1] = pack2(f0[2], f0[3]);
        v[2] = pack2(f1[0], f1[1]); v[3] = pack2(f1[2], f1[3]);
      }
      int off = (r << 8) + (((kc << 1)) ^ ((r & 7) << 4));
      *reinterpret_cast<i32x4*>(&smem[off]) = v;
    }
#pragma unroll
    for (int i = 0; i < 4; ++i) {
      int c = tid + (i << 8);
      int n = c >> 4, kc = (c & 15) << 3;
      i32x4 v = *reinterpret_cast<const i32x4*>(B1t + (size_t)(n1 + n) * KK + kbase + kc);
      int off = 8192 + (n << 8) + (((kc << 1)) ^ ((n & 7) << 4));
      *reinterpret_cast<i32x4*>(&smem[off]) = v;
    }
    __syncthreads();
#pragma unroll
    for (int ks = 0; ks < 4; ++ks) {
      int kbyte = ks * 64 + l4 * 16;
      int ra = wm * 16 + l15;
      short8 a = *reinterpret_cast<short8*>(&smem[(ra << 8) + (kbyte ^ ((ra & 7) << 4))]);
      int nb0 = wn * 32 + l15;
      short8 b0 = *reinterpret_cast<short8*>(&smem[8192 + (nb0 << 8) + (kbyte ^ ((nb0 & 7) << 4))]);
      int nb1 = nb0 + 16;
      short8 b1 = *reinterpret_cast<short8*>(&smem[8192 + (nb1 << 8) + (kbyte ^ ((nb1 & 7) << 4))]);
      acc0 = __builtin_amdgcn_mfma_f32_16x16x32_bf16(a, b0, acc0, 0, 0, 0);
      acc1 = __builtin_amdgcn_mfma_f32_16x16x32_bf16(a, b1, acc1, 0, 0, 0);
    }
    __syncthreads();
  }
  int mrow = m0 + wm * 16 + l4 * 4;
#pragma unroll
  for (int f = 0; f < 2; ++f) {
    f32x4 av = f ? acc1 : acc0;
    int c = n1 + wn * 32 + f * 16 + l15;
#pragma unroll
    for (int j = 0; j < 4; ++j) {
      int m = mrow + j;
      float v = av[j];
      if (c < NH) {
        zfb[(size_t)m * NH + c] = sigmoidf_(v + bz[c]);
      } else {
        int cc = c - NH;
        float rv = sigmoidf_(v + br[cc]);
        rhb[(size_t)m * NH + cc] = f2bf(rv * hf[(size_t)m * NH + cc]);
      }
    }
  }
}

__global__ void __launch_bounds__(256)
gru_phase2(const float* __restrict__ x, const ushort_t* __restrict__ B2t,
           ushort_t* __restrict__ hb, const ushort_t* __restrict__ rhb,
           float* __restrict__ hf, const float* __restrict__ zfb,
           const float* __restrict__ bb, float* __restrict__ out, int t) {
  __shared__ __align__(16) char smem[16384];
  const int tid  = threadIdx.x;
  const int bid  = blockIdx.x;
  const int lane = tid & 63;
  const int w    = tid >> 6;
  const int wm   = w >> 1, wn = w & 1;
  const int m0   = (bid >> 5) * 32;
  const int n2   = (bid & 31) * 32;
  const int l15  = lane & 15, l4 = lane >> 4;

  f32x4 acc = {0.f, 0.f, 0.f, 0.f};
  for (int kb = 0; kb < KK / BK; ++kb) {
    const int kbase = kb * BK;
#pragma unroll
    for (int i = 0; i < 2; ++i) {
      int c = tid + (i << 8);
      int r = c >> 4, kc = (c & 15) << 3;
      int m = m0 + r, k = kbase + kc;
      i32x4 v;
      if (k < NH) {
        v = *reinterpret_cast<const i32x4*>(rhb + (size_t)m * NH + k);
      } else {
        const float* xp = x + (size_t)m * (NT * ND) + (size_t)t * ND + (k - NH);
        f32x4 f0 = *reinterpret_cast<const f32x4*>(xp);
        f32x4 f1 = *reinterpret_cast<const f32x4*>(xp + 4);
        v[0] = pack2(f0[0], f0[1]); v[1] = pack2(f0[2], f0[3]);
        v[2] = pack2(f1[0], f1[1]); v[3] = pack2(f1[2], f1[3]);
      }
      int off = (r << 8) + (((kc << 1)) ^ ((r & 7) << 4));
      *reinterpret_cast<i32x4*>(&smem[off]) = v;
    }
#pragma unroll
    for (int i = 0; i < 2; ++i) {
      int c = tid + (i << 8);
      int n = c >> 4, kc = (c & 15) << 3;
      i32x4 v = *reinterpret_cast<const i32x4*>(B2t + (size_t)(n2 + n) * KK + kbase + kc);
      int off = 8192 + (n << 8) + (((kc << 1)) ^ ((n & 7) << 4));
      *reinterpret_cast<i32x4*>(&smem[off]) = v;
    }
    __syncthreads();
#pragma unroll
    for (int ks = 0; ks < 4; ++ks) {
      int kbyte = ks * 64 + l4 * 16;
      int ra = wm * 16 + l15;
      short8 a = *reinterpret_cast<short8*>(&smem[(ra << 8) + (kbyte ^ ((ra & 7) << 4))]);
      int nb = wn * 16 + l15;
      short8 b0 = *reinterpret_cast<short8*>(&smem[8192 + (nb << 8) + (kbyte ^ ((nb & 7) << 4))]);
      acc = __builtin_amdgcn_mfma_f32_16x16x32_bf16(a, b0, acc, 0, 0, 0);
    }
    __syncthreads();
  }
  int mrow = m0 + wm * 16 + l4 * 4;
  int c = n2 + wn * 16 + l15;
#pragma unroll
  for (int j = 0; j < 4; ++j) {
    int m = mrow + j;
    size_t idx = (size_t)m * NH + c;
    float hc = tanhf_(acc[j] + bb[c]);
    float zv = zfb[idx];
    float hn = (1.f - zv) * hf[idx] + zv * hc;
    hf[idx] = hn;
    hb[idx] = f2bf(hn);
    if (t == NT - 1) out[idx] = hn;
  }
}

// ===========================================================================
extern "C" void kernel_launch(void* const* d_in, const int* in_sizes, int n_in,
                              void* d_out, int out_size, void* d_ws, size_t ws_size,
                              hipStream_t stream) {
  const float* x  = (const float*)d_in[0];
  const float* W  = (const float*)d_in[1];
  const float* U  = (const float*)d_in[2];
  const float* Wz = (const float*)d_in[3];
  const float* Uz = (const float*)d_in[4];
  const float* Wr = (const float*)d_in[5];
  const float* Ur = (const float*)d_in[6];
  const float* bb = (const float*)d_in[7];
  const float* bz = (const float*)d_in[8];
  const float* br = (const float*)d_in[9];
  float* out = (float*)d_out;
  char* ws = (char*)d_ws;

  ushort_t* Bu1   = (ushort_t*)(ws);                  //  4,194,304
  ushort_t* Bu2   = (ushort_t*)(ws + 4194304);        //  2,097,152
  ushort_t* Bx    = (ushort_t*)(ws + 6291456);        //  3,145,728
  ushort_t* hb    = (ushort_t*)(ws + 9437184);        //    524,288
  ushort_t* rhb   = (ushort_t*)(ws + 9961472);        //    524,288
  float*    hf    = (float*)   (ws + 10485760);       //  1,048,576
  float*    zfb   = (float*)   (ws + 11534336);       //  1,048,576
  ushort_t* Gx    = (ushort_t*)(ws + 12587008);       // 805,306,368 -> 817,893,376

  const bool fast = (ws_size >= (size_t)817893376ULL);

  if (fast) {
    (void)hipFuncSetAttribute(reinterpret_cast<const void*>(&p1k4),
                              hipFuncAttributeMaxDynamicSharedMemorySize, 98304);
    hipLaunchKernelGGL(repackT, dim3(16, 16), dim3(256), 0, stream, Uz, Bu1, NH);
    hipLaunchKernelGGL(repackT, dim3(16, 16), dim3(256), 0, stream, Ur, Bu1 + (size_t)NH * NH, NH);
    hipLaunchKernelGGL(repackT, dim3(16, 16), dim3(256), 0, stream, U,  Bu2, NH);
    hipLaunchKernelGGL(repackT, dim3(8, 16),  dim3(256), 0, stream, Wz, Bx, ND);
    hipLaunchKernelGGL(repackT, dim3(8, 16),  dim3(256), 0, stream, Wr, Bx + (size_t)NH * ND, ND);
    hipLaunchKernelGGL(repackT, dim3(8, 16),  dim3(256), 0, stream, W,  Bx + (size_t)2 * NH * ND, ND);
    hipLaunchKernelGGL(init_state, dim3(1024), dim3(256), 0, stream, hb, hf);
    hipLaunchKernelGGL(gxgemm2, dim3(1024, 24), dim3(256), 0, stream, x, Bx, bz, br, bb, Gx);
    for (int t = 0; t < NT; ++t) {
      hipLaunchKernelGGL(p1k4, dim3(256), dim3(512), 98304, stream,
                         Bu1, hb, rhb, hf, zfb, Gx, t);
      hipLaunchKernelGGL(p2k4, dim3(256), dim3(512), 0, stream,
                         Bu2, rhb, hb, hf, zfb, Gx, out, t);
    }
  } else {
    // fallback: proven round-2 per-step path (K=1536, biases in-loop)
    ushort_t* B1t  = (ushort_t*)(ws);
    ushort_t* B2t  = (ushort_t*)(ws + 6291456);
    ushort_t* hb2  = (ushort_t*)(ws + 9437184);
    ushort_t* rhb2 = (ushort_t*)(ws + 9961472);
    float*    hf2  = (float*)   (ws + 10485760);
    float*    zfb2 = (float*)   (ws + 11534336);
    hipLaunchKernelGGL(repack_weights, dim3(24, 32, 2), dim3(256), 0, stream,
                       U, W, Uz, Wz, Ur, Wr, B1t, B2t);
    hipLaunchKernelGGL(init_state, dim3(1024), dim3(256), 0, stream, hb2, hf2);
    for (int t = 0; t < NT; ++t) {
      hipLaunchKernelGGL(gru_phase1, dim3(256), dim3(256), 0, stream,
                         x, B1t, hb2, rhb2, hf2, zfb2, bz, br, t);
      hipLaunchKernelGGL(gru_phase2, dim3(256), dim3(256), 0, stream,
                         x, B2t, hb2, rhb2, hf2, zfb2, bb, out, t);
    }
  }
}

// Round 13
// 7747.667 us; speedup vs baseline: 4.3988x; 1.0107x over previous
//
#include <hip/hip_runtime.h>

typedef unsigned short ushort_t;
typedef __attribute__((ext_vector_type(8))) short short8;
typedef __attribute__((ext_vector_type(4))) float f32x4;
typedef __attribute__((ext_vector_type(4))) int i32x4;

#define NB   256     // batch
#define NT   512     // timesteps
#define ND   512     // input dim
#define NH   1024    // hidden dim
#define KK   1536    // NH + ND (fallback path concat K)
#define BK   128

__device__ __forceinline__ ushort_t f2bf(float f) {
  union { float f; unsigned u; } v; v.f = f;
  unsigned u = v.u;
  return (ushort_t)((u + 0x7FFFu + ((u >> 16) & 1u)) >> 16);
}
__device__ __forceinline__ int pack2(float a, float b) {
  return (int)(((unsigned)f2bf(b) << 16) | (unsigned)f2bf(a));
}
__device__ __forceinline__ float bf2f(ushort_t h) {
  union { unsigned u; float f; } v; v.u = ((unsigned)h) << 16; return v.f;
}
__device__ __forceinline__ float sigmoidf_(float x) {
  return 1.f / (1.f + __expf(-x));
}
__device__ __forceinline__ float tanhf_(float x) {
  return 1.f - 2.f / (__expf(2.f * x) + 1.f);
}

// ===========================================================================
// Fused prep: all 6 weight repacks (verified repackT body) + state init in ONE
// launch. grid (16,16,7), 256 thr. z=0..2: K=1024 repacks; z=3..5: K=512
// (kt<8); z=6: init hb/hf.
// ===========================================================================
__device__ __forceinline__ void repack_body(const float* __restrict__ src,
                                            ushort_t* __restrict__ dst, int K,
                                            int k0, int n0, int tid,
                                            float (*tile)[65]) {
  for (int i = 0; i < 16; ++i) {
    int e = tid + i * 256;
    int r = e >> 6, c = e & 63;
    tile[r][c] = src[(size_t)(k0 + r) * 1024 + n0 + c];
  }
  __syncthreads();
  for (int i = 0; i < 2; ++i) {
    int cch = tid + i * 256;
    int nl = cch >> 3, kc = (cch & 7) * 8;
    ushort_t tmp[8];
#pragma unroll
    for (int j = 0; j < 8; ++j) tmp[j] = f2bf(tile[kc + j][nl]);
    *reinterpret_cast<i32x4*>(dst + (size_t)(n0 + nl) * K + k0 + kc) =
        *reinterpret_cast<i32x4*>(tmp);
  }
}

__global__ void prep_all(const float* __restrict__ U,  const float* __restrict__ W,
                         const float* __restrict__ Uz, const float* __restrict__ Wz,
                         const float* __restrict__ Ur, const float* __restrict__ Wr,
                         ushort_t* __restrict__ Bu1, ushort_t* __restrict__ Bu2,
                         ushort_t* __restrict__ Bx,
                         ushort_t* __restrict__ hb, float* __restrict__ hf) {
  __shared__ float tile[64][65];
  const int z = blockIdx.z, kt = blockIdx.x, nt = blockIdx.y;
  const int tid = threadIdx.x;
  if (z == 6) {
    int i = (nt * 16 + kt) * 1024 + tid * 4;    // 256 blocks x 1024 elems
    *reinterpret_cast<unsigned long long*>(hb + i) = 0ULL;
    f32x4 zf = {0.f, 0.f, 0.f, 0.f};
    *reinterpret_cast<f32x4*>(hf + i) = zf;
    return;
  }
  const float* src; ushort_t* dst; int K;
  switch (z) {
    case 0: src = Uz; dst = Bu1;                        K = 1024; break;
    case 1: src = Ur; dst = Bu1 + (size_t)NH * NH;      K = 1024; break;
    case 2: src = U;  dst = Bu2;                        K = 1024; break;
    case 3: src = Wz; dst = Bx;                         K = 512;  break;
    case 4: src = Wr; dst = Bx + (size_t)NH * ND;       K = 512;  break;
    default: src = W; dst = Bx + (size_t)2 * NH * ND;   K = 512;  break;
  }
  if (K == 512 && kt >= 8) return;
  repack_body(src, dst, K, kt * 64, nt * 64, tid, tile);
}

// ===========================================================================
// Gx precompute v3 (128x128 tile, BK=64; LOAD-after-barrier schedule):
// Gx[t*256+b][j], j: 0..1023=z, 1024..2047=r, 2048..3071=cand.
// Bx bf16 [3072][512] n-major. grid (1024, 24), 256 thr.
// ===========================================================================
#define GOFF(row_, kc8_) (((((row_) * 8 + (kc8_)) << 4)) ^ (((row_) & 7) << 4))

__global__ void __launch_bounds__(256)
gxgemm3(const float* __restrict__ x, const ushort_t* __restrict__ Bx,
        const float* __restrict__ bz, const float* __restrict__ br,
        const float* __restrict__ bb, ushort_t* __restrict__ Gx) {
  __shared__ __align__(16) char smem[65536];   // 2 x (A 16KB + B 16KB)
  const int tid  = threadIdx.x;
  const int m0   = blockIdx.x * 128;
  const int n0   = blockIdx.y * 128;
  const int lane = tid & 63;
  const int w    = tid >> 6;
  const int wm   = w >> 1, wn = w & 1;
  const int l15  = lane & 15, l4 = lane >> 4;
  const int tt   = m0 >> 8;
  const int b0   = m0 & 255;

  f32x4 rxa[4][2];
  i32x4 rxb[4];

#define GX_LOAD(kb_) do {                                                     \
    int kbase_ = (kb_) * 64;                                                  \
    _Pragma("unroll")                                                         \
    for (int i_ = 0; i_ < 4; ++i_) {                                          \
      int c_ = tid + i_ * 256;                                                \
      int row_ = c_ >> 3, kc8_ = c_ & 7;                                      \
      const float* xp_ = x + ((size_t)(b0 + row_) * NT + tt) * ND             \
                          + kbase_ + kc8_ * 8;                                \
      rxa[i_][0] = *reinterpret_cast<const f32x4*>(xp_);                      \
      rxa[i_][1] = *reinterpret_cast<const f32x4*>(xp_ + 4);                  \
      rxb[i_] = *reinterpret_cast<const i32x4*>(                              \
          Bx + (size_t)(n0 + row_) * 512 + kbase_ + kc8_ * 8);                \
    }                                                                         \
  } while (0)

#define GX_WRITE(p_) do {                                                     \
    char* ab_ = smem + (p_) * 32768;                                          \
    _Pragma("unroll")                                                         \
    for (int i_ = 0; i_ < 4; ++i_) {                                          \
      int c_ = tid + i_ * 256;                                                \
      int row_ = c_ >> 3, kc8_ = c_ & 7;                                      \
      i32x4 v_;                                                               \
      v_[0] = pack2(rxa[i_][0][0], rxa[i_][0][1]);                            \
      v_[1] = pack2(rxa[i_][0][2], rxa[i_][0][3]);                            \
      v_[2] = pack2(rxa[i_][1][0], rxa[i_][1][1]);                            \
      v_[3] = pack2(rxa[i_][1][2], rxa[i_][1][3]);                            \
      *reinterpret_cast<i32x4*>(ab_ + GOFF(row_, kc8_)) = v_;                 \
      *reinterpret_cast<i32x4*>(ab_ + 16384 + GOFF(row_, kc8_)) = rxb[i_];    \
    }                                                                         \
  } while (0)

#define GX_MFMA(p_) do {                                                      \
    char* base_ = smem + (p_) * 32768;                                        \
    _Pragma("unroll")                                                         \
    for (int ks_ = 0; ks_ < 2; ++ks_) {                                       \
      int kc8_ = ks_ * 4 + l4;                                                \
      short8 a_[4], bf_[4];                                                   \
      _Pragma("unroll")                                                       \
      for (int i_ = 0; i_ < 4; ++i_) {                                        \
        int row_ = wm * 64 + i_ * 16 + l15;                                   \
        a_[i_] = *reinterpret_cast<short8*>(base_ + GOFF(row_, kc8_));        \
        int col_ = wn * 64 + i_ * 16 + l15;                                   \
        bf_[i_] = *reinterpret_cast<short8*>(base_ + 16384 + GOFF(col_, kc8_));\
      }                                                                       \
      _Pragma("unroll")                                                       \
      for (int i_ = 0; i_ < 4; ++i_)                                          \
        _Pragma("unroll")                                                     \
        for (int j_ = 0; j_ < 4; ++j_)                                        \
          acc[i_][j_] = __builtin_amdgcn_mfma_f32_16x16x32_bf16(              \
              a_[i_], bf_[j_], acc[i_][j_], 0, 0, 0);                         \
    }                                                                         \
  } while (0)

  f32x4 acc[4][4];
#pragma unroll
  for (int i = 0; i < 4; ++i)
#pragma unroll
    for (int j = 0; j < 4; ++j) acc[i][j] = (f32x4){0.f, 0.f, 0.f, 0.f};

  GX_LOAD(0);
  GX_WRITE(0);
#pragma unroll
  for (int kb = 0; kb < 8; ++kb) {
    const int p = kb & 1;
    __syncthreads();
    if (kb < 7) GX_LOAD(kb + 1);
    GX_MFMA(p);
    if (kb < 7) {
      __builtin_amdgcn_sched_barrier(0);
      GX_WRITE(p ^ 1);
    }
  }
#undef GX_LOAD
#undef GX_WRITE
#undef GX_MFMA

#pragma unroll
  for (int j = 0; j < 4; ++j) {
    int col = n0 + wn * 64 + j * 16 + l15;
    float bias = (col < NH) ? bz[col] : (col < 2 * NH ? br[col - NH] : bb[col - 2 * NH]);
#pragma unroll
    for (int i = 0; i < 4; ++i) {
      int mr = m0 + wm * 64 + i * 16 + 4 * l4;
#pragma unroll
      for (int jj = 0; jj < 4; ++jj)
        Gx[(size_t)(mr + jj) * 3072 + col] = f2bf(acc[i][j][jj] + bias);
    }
  }
}

// ===========================================================================
// Phase 1 v5 (LOAD-after-barrier schedule): 512 thr, grid 256 = 8 mt(32 rows)
// x 32 nt(64 cols of 2048). XCD-pinned (nt%8 = bid%8). BK=256, 4 iters.
// Per iter: sync; LOAD(kb+1); MFMA(buf p); WRITE(buf p^1)  -> loads fly under
// MFMA inside the iteration (no pre-barrier vmcnt drain of prefetch).
// LDS 2 x (16KB A + 32KB B) = 96KB dynamic. Wave w: 16x16 tile, 32 MFMA.
// ===========================================================================
__global__ void __launch_bounds__(512)
p1k5(const ushort_t* __restrict__ Bu1, const ushort_t* __restrict__ hb,
     ushort_t* __restrict__ rhb, const float* __restrict__ hf,
     float* __restrict__ zfb, const ushort_t* __restrict__ Gx, int t) {
  extern __shared__ __align__(16) char dsm[];   // 98304
  const int tid  = threadIdx.x;
  const int bid  = blockIdx.x;
  const int lane = tid & 63;
  const int w    = tid >> 6;
  const int l15  = lane & 15, l4 = lane >> 4;
  const int nt   = bid & 31;
  const int mt   = bid >> 5;
  const int m0   = mt * 32;
  const int n1   = nt * 64;
  const int msub = w >> 2, nsub = w & 3;
  const bool zside = (nt < 16);

  const int akc8 = tid & 31, arow = tid >> 5;
  i32x4 ra[2], rb[4];

#define P1_LOAD(kb_) do {                                                     \
    const ushort_t* hsrc_ = hb + (size_t)m0 * NH + (kb_) * 256 + akc8 * 8;    \
    ra[0] = *reinterpret_cast<const i32x4*>(hsrc_ + (size_t)arow * NH);       \
    ra[1] = *reinterpret_cast<const i32x4*>(hsrc_ + (size_t)(arow + 16) * NH);\
    const ushort_t* bsrc_ = Bu1 + (size_t)n1 * NH + (kb_) * 256 + akc8 * 8;   \
    _Pragma("unroll")                                                         \
    for (int i_ = 0; i_ < 4; ++i_)                                            \
      rb[i_] = *reinterpret_cast<const i32x4*>(                               \
          bsrc_ + (size_t)(arow + 16 * i_) * NH);                             \
  } while (0)

#define P1_WRITE(p_) do {                                                     \
    char* ab_ = dsm + (p_) * 49152;                                           \
    *reinterpret_cast<i32x4*>(ab_ +                                           \
        (((akc8 * 32 + arow) * 16) ^ ((akc8 & 7) << 4))) = ra[0];             \
    *reinterpret_cast<i32x4*>(ab_ +                                           \
        (((akc8 * 32 + arow + 16) * 16) ^ ((akc8 & 7) << 4))) = ra[1];        \
    char* bbase_ = ab_ + 16384;                                               \
    _Pragma("unroll")                                                         \
    for (int i_ = 0; i_ < 4; ++i_)                                            \
      *reinterpret_cast<i32x4*>(bbase_ +                                      \
          (((akc8 * 64 + arow + 16 * i_) * 16) ^ ((akc8 & 7) << 4))) = rb[i_];\
  } while (0)

#define P1_MFMA(p_) do {                                                      \
    char* base_ = dsm + (p_) * 49152;                                         \
    _Pragma("unroll")                                                         \
    for (int s_ = 0; s_ < 8; ++s_) {                                          \
      int kc8_ = s_ * 4 + l4;                                                 \
      short8 a_ = *reinterpret_cast<short8*>(base_ +                          \
          (((kc8_ * 32 + msub * 16 + l15) * 16) ^ ((kc8_ & 7) << 4)));        \
      short8 b_ = *reinterpret_cast<short8*>(base_ + 16384 +                  \
          (((kc8_ * 64 + nsub * 16 + l15) * 16) ^ ((kc8_ & 7) << 4)));        \
      acc = __builtin_amdgcn_mfma_f32_16x16x32_bf16(a_, b_, acc, 0, 0, 0);    \
    }                                                                         \
  } while (0)

  P1_LOAD(0);

  // epilogue operand prefetch (issued with prologue; drains at first barrier)
  const int mrow = m0 + msub * 16 + 4 * l4;
  const int col1 = n1 + nsub * 16 + l15;
  const size_t gxrow = (size_t)t * NB * 3072;
  float gxe[4], hfe[4];
#pragma unroll
  for (int jj = 0; jj < 4; ++jj) {
    gxe[jj] = bf2f(Gx[gxrow + (size_t)(mrow + jj) * 3072 + col1]);
    if (!zside) hfe[jj] = hf[(size_t)(mrow + jj) * NH + (col1 - NH)];
  }

  P1_WRITE(0);

  f32x4 acc = {0.f, 0.f, 0.f, 0.f};
  // kb=0
  __syncthreads();
  P1_LOAD(1);
  P1_MFMA(0);
  __builtin_amdgcn_sched_barrier(0);
  P1_WRITE(1);
  // kb=1
  __syncthreads();
  P1_LOAD(2);
  P1_MFMA(1);
  __builtin_amdgcn_sched_barrier(0);
  P1_WRITE(0);
  // kb=2
  __syncthreads();
  P1_LOAD(3);
  P1_MFMA(0);
  __builtin_amdgcn_sched_barrier(0);
  P1_WRITE(1);
  // kb=3
  __syncthreads();
  P1_MFMA(1);
#undef P1_LOAD
#undef P1_WRITE
#undef P1_MFMA

  if (zside) {
#pragma unroll
    for (int jj = 0; jj < 4; ++jj)
      zfb[(size_t)(mrow + jj) * NH + col1] = sigmoidf_(acc[jj] + gxe[jj]);
  } else {
    int cc = col1 - NH;
#pragma unroll
    for (int jj = 0; jj < 4; ++jj) {
      float rv = sigmoidf_(acc[jj] + gxe[jj]);
      rhb[(size_t)(mrow + jj) * NH + cc] = f2bf(rv * hfe[jj]);
    }
  }
}

// ===========================================================================
// Phase 2 v5 (LOAD-after-barrier schedule): 512 thr, grid 256 = 8 mt(32 rows)
// x 32 nt(32 cols of 1024). BK=256, 4 iters. Wave (msub=w&1, nsub=(w>>1)&1,
// kh=w>>2): 16x16 tile over K-half -> 16 MFMA; pair reduction (w, w+4) via
// LDS with a single sync. 64KB static.
// ===========================================================================
__global__ void __launch_bounds__(512)
p2k5(const ushort_t* __restrict__ Bu2, const ushort_t* __restrict__ rhb,
     ushort_t* __restrict__ hb, float* __restrict__ hf,
     const float* __restrict__ zfb, const ushort_t* __restrict__ Gx,
     float* __restrict__ out, int t) {
  __shared__ __align__(16) char smem[65536];    // 2 x (16KB A + 16KB B)
  const int tid  = threadIdx.x;
  const int bid  = blockIdx.x;
  const int lane = tid & 63;
  const int w    = tid >> 6;
  const int l15  = lane & 15, l4 = lane >> 4;
  const int nt   = bid & 31;
  const int mt   = bid >> 5;
  const int m0   = mt * 32;
  const int n2   = nt * 32;
  const int msub = w & 1, nsub = (w >> 1) & 1, kh = w >> 2;

  const int akc8 = tid & 31, arow = tid >> 5;
  i32x4 ra[2], rb[2];

#define P2_LOAD(kb_) do {                                                     \
    const ushort_t* asrc_ = rhb + (size_t)m0 * NH + (kb_) * 256 + akc8 * 8;   \
    ra[0] = *reinterpret_cast<const i32x4*>(asrc_ + (size_t)arow * NH);       \
    ra[1] = *reinterpret_cast<const i32x4*>(asrc_ + (size_t)(arow + 16) * NH);\
    const ushort_t* bsrc_ = Bu2 + (size_t)n2 * NH + (kb_) * 256 + akc8 * 8;   \
    rb[0] = *reinterpret_cast<const i32x4*>(bsrc_ + (size_t)arow * NH);       \
    rb[1] = *reinterpret_cast<const i32x4*>(bsrc_ + (size_t)(arow + 16) * NH);\
  } while (0)

#define P2_WRITE(p_) do {                                                     \
    char* ab_ = smem + (p_) * 32768;                                          \
    *reinterpret_cast<i32x4*>(ab_ +                                           \
        (((akc8 * 32 + arow) * 16) ^ ((akc8 & 7) << 4))) = ra[0];             \
    *reinterpret_cast<i32x4*>(ab_ +                                           \
        (((akc8 * 32 + arow + 16) * 16) ^ ((akc8 & 7) << 4))) = ra[1];        \
    char* bbase_ = ab_ + 16384;                                               \
    *reinterpret_cast<i32x4*>(bbase_ +                                        \
        (((akc8 * 32 + arow) * 16) ^ ((akc8 & 7) << 4))) = rb[0];             \
    *reinterpret_cast<i32x4*>(bbase_ +                                        \
        (((akc8 * 32 + arow + 16) * 16) ^ ((akc8 & 7) << 4))) = rb[1];        \
  } while (0)

#define P2_MFMA(p_) do {                                                      \
    char* base_ = smem + (p_) * 32768;                                        \
    _Pragma("unroll")                                                         \
    for (int s_ = 0; s_ < 4; ++s_) {                                          \
      int kc8_ = kh * 16 + s_ * 4 + l4;                                       \
      short8 a_ = *reinterpret_cast<short8*>(base_ +                          \
          (((kc8_ * 32 + msub * 16 + l15) * 16) ^ ((kc8_ & 7) << 4)));        \
      short8 b_ = *reinterpret_cast<short8*>(base_ + 16384 +                  \
          (((kc8_ * 32 + nsub * 16 + l15) * 16) ^ ((kc8_ & 7) << 4)));        \
      acc = __builtin_amdgcn_mfma_f32_16x16x32_bf16(a_, b_, acc, 0, 0, 0);    \
    }                                                                         \
  } while (0)

  P2_LOAD(0);

  // epilogue operands (waves 0..3 own output tiles)
  const int mrow = m0 + msub * 16 + 4 * l4;
  const int colw = n2 + ((w >> 1) & 1) * 16 + l15;     // valid for w<4
  const size_t gxrow = (size_t)t * NB * 3072;
  float gxe[4], hfe[4], ze[4];
  if (w < 4) {
#pragma unroll
    for (int jj = 0; jj < 4; ++jj) {
      gxe[jj] = bf2f(Gx[gxrow + (size_t)(mrow + jj) * 3072 + 2048 + colw]);
      hfe[jj] = hf[(size_t)(mrow + jj) * NH + colw];
      ze[jj]  = zfb[(size_t)(mrow + jj) * NH + colw];
    }
  }

  P2_WRITE(0);

  f32x4 acc = {0.f, 0.f, 0.f, 0.f};
  // kb=0
  __syncthreads();
  P2_LOAD(1);
  P2_MFMA(0);
  __builtin_amdgcn_sched_barrier(0);
  P2_WRITE(1);
  // kb=1
  __syncthreads();
  P2_LOAD(2);
  P2_MFMA(1);
  __builtin_amdgcn_sched_barrier(0);
  P2_WRITE(0);
  // kb=2
  __syncthreads();
  P2_LOAD(3);
  P2_MFMA(0);
  __builtin_amdgcn_sched_barrier(0);
  P2_WRITE(1);
  // kb=3
  __syncthreads();
  P2_MFMA(1);
#undef P2_LOAD
#undef P2_WRITE
#undef P2_MFMA

  // pair reduction: wave w+4 -> wave w (buf0 region is free; single sync)
  if (w >= 4)
    *reinterpret_cast<f32x4*>(smem + (w - 4) * 1024 + lane * 16) = acc;
  __syncthreads();
  if (w < 4) {
    f32x4 v = acc + *reinterpret_cast<f32x4*>(smem + w * 1024 + lane * 16);
#pragma unroll
    for (int jj = 0; jj < 4; ++jj) {
      size_t idx = (size_t)(mrow + jj) * NH + colw;
      float hc = tanhf_(v[jj] + gxe[jj]);
      float zv = ze[jj];
      float hn = (1.f - zv) * hfe[jj] + zv * hc;
      hf[idx] = hn;
      hb[idx] = f2bf(hn);
      if (t == NT - 1) out[idx] = hn;
    }
  }
}

// ===========================================================================
// ============== FALLBACK (round-2, proven): per-step, K=1536 ===============
// ===========================================================================
__global__ void repack_weights(const float* __restrict__ U,  const float* __restrict__ W,
                               const float* __restrict__ Uz, const float* __restrict__ Wz,
                               const float* __restrict__ Ur, const float* __restrict__ Wr,
                               ushort_t* __restrict__ B1t, ushort_t* __restrict__ B2t) {
  const int kt = blockIdx.x, nt = blockIdx.y, which = blockIdx.z;
  if (which == 1 && nt >= 16) return;
  __shared__ float tile[64][65];
  const int k0 = kt * 64, n0 = nt * 64;
  const int tid = threadIdx.x;
  for (int i = 0; i < 16; ++i) {
    int e = tid + i * 256;
    int r = e >> 6, c = e & 63;
    int k = k0 + r, n = n0 + c;
    int nn = n & 1023;
    const float* src;
    if (which == 0) {
      if (k < NH) src = (n < NH ? Uz : Ur) + (size_t)k * NH + nn;
      else        src = (n < NH ? Wz : Wr) + (size_t)(k - NH) * NH + nn;
    } else {
      if (k < NH) src = U + (size_t)k * NH + nn;
      else        src = W + (size_t)(k - NH) * NH + nn;
    }
    tile[r][c] = *src;
  }
  __syncthreads();
  ushort_t* dst = (which == 0) ? B1t : B2t;
  for (int i = 0; i < 2; ++i) {
    int cch = tid + i * 256;
    int nl = cch >> 3, kc = (cch & 7) * 8;
    ushort_t tmp[8];
#pragma unroll
    for (int j = 0; j < 8; ++j) tmp[j] = f2bf(tile[kc + j][nl]);
    *reinterpret_cast<i32x4*>(dst + (size_t)(n0 + nl) * KK + k0 + kc) =
        *reinterpret_cast<i32x4*>(tmp);
  }
}

__global__ void init_state(ushort_t* __restrict__ hb, float* __restrict__ hf) {
  int i = blockIdx.x * 256 + threadIdx.x;
  if (i < NB * NH) { hb[i] = 0; hf[i] = 0.f; }
}

__global__ void __launch_bounds__(256)
gru_phase1(const float* __restrict__ x, const ushort_t* __restrict__ B1t,
           const ushort_t* __restrict__ hb, ushort_t* __restrict__ rhb,
           const float* __restrict__ hf, float* __restrict__ zfb,
           const float* __restrict__ bz, const float* __restrict__ br, int t) {
  __shared__ __align__(16) char smem[24576];
  const int tid  = threadIdx.x;
  const int bid  = blockIdx.x;
  const int lane = tid & 63;
  const int w    = tid >> 6;
  const int wm   = w >> 1, wn = w & 1;
  const int m0   = (bid >> 5) * 32;
  const int n1   = (bid & 31) * 64;
  const int l15  = lane & 15, l4 = lane >> 4;

  f32x4 acc0 = {0.f, 0.f, 0.f, 0.f}, acc1 = {0.f, 0.f, 0.f, 0.f};
  for (int kb = 0; kb < KK / BK; ++kb) {
    const int kbase = kb * BK;
#pragma unroll
    for (int i = 0; i < 2; ++i) {
      int c = tid + (i << 8);
      int r = c >> 4, kc = (c & 15) << 3;
      int m = m0 + r, k = kbase + kc;
      i32x4 v;
      if (k < NH) {
        v = *reinterpret_cast<const i32x4*>(hb + (size_t)m * NH + k);
      } else {
        const float* xp = x + (size_t)m * (NT * ND) + (size_t)t * ND + (k - NH);
        f32x4 f0 = *reinterpret_cast<const f32x4*>(xp);
        f32x4 f1 = *reinterpret_cast<const f32x4*>(xp + 4);
        v[0] = pack2(f0[0], f0[1]); v[1] = pack2(f0[2], f0[3]);
        v[2] = pack2(f1[0], f1[1]); v[3] = pack2(f1[2], f1[3]);
      }
      int off = (r << 8) + (((kc << 1)) ^ ((r & 7) << 4));
      *reinterpret_cast<i32x4*>(&smem[off]) = v;
    }
#pragma unroll
    for (int i = 0; i < 4; ++i) {
      int c = tid + (i << 8);
      int n = c >> 4, kc = (c & 15) << 3;
      i32x4 v = *reinterpret_cast<const i32x4*>(B1t + (size_t)(n1 + n) * KK + kbase + kc);
      int off = 8192 + (n << 8) + (((kc << 1)) ^ ((n & 7) << 4));
      *reinterpret_cast<i32x4*>(&smem[off]) = v;
    }
    __syncthreads();
#pragma unroll
    for (int ks = 0; ks < 4; ++ks) {
      int kbyte = ks * 64 + l4 * 16;
      int ra = wm * 16 + l15;
      short8 a = *reinterpret_cast<short8*>(&smem[(ra << 8) + (kbyte ^ ((ra & 7) << 4))]);
      int nb0 = wn * 32 + l15;
      short8 b0 = *reinterpret_cast<short8*>(&smem[8192 + (nb0 << 8) + (kbyte ^ ((nb0 & 7) << 4))]);
      int nb1 = nb0 + 16;
      short8 b1 = *reinterpret_cast<short8*>(&smem[8192 + (nb1 << 8) + (kbyte ^ ((nb1 & 7) << 4))]);
      acc0 = __builtin_amdgcn_mfma_f32_16x16x32_bf16(a, b0, acc0, 0, 0, 0);
      acc1 = __builtin_amdgcn_mfma_f32_16x16x32_bf16(a, b1, acc1, 0, 0, 0);
    }
    __syncthreads();
  }
  int mrow = m0 + wm * 16 + l4 * 4;
#pragma unroll
  for (int f = 0; f < 2; ++f) {
    f32x4 av = f ? acc1 : acc0;
    int c = n1 + wn * 32 + f * 16 + l15;
#pragma unroll
    for (int j = 0; j < 4; ++j) {
      int m = mrow + j;
      float v = av[j];
      if (c < NH) {
        zfb[(size_t)m * NH + c] = sigmoidf_(v + bz[c]);
      } else {
        int cc = c - NH;
        float rv = sigmoidf_(v + br[cc]);
        rhb[(size_t)m * NH + cc] = f2bf(rv * hf[(size_t)m * NH + cc]);
      }
    }
  }
}

__global__ void __launch_bounds__(256)
gru_phase2(const float* __restrict__ x, const ushort_t* __restrict__ B2t,
           ushort_t* __restrict__ hb, const ushort_t* __restrict__ rhb,
           float* __restrict__ hf, const float* __restrict__ zfb,
           const float* __restrict__ bb, float* __restrict__ out, int t) {
  __shared__ __align__(16) char smem[16384];
  const int tid  = threadIdx.x;
  const int bid  = blockIdx.x;
  const int lane = tid & 63;
  const int w    = tid >> 6;
  const int wm   = w >> 1, wn = w & 1;
  const int m0   = (bid >> 5) * 32;
  const int n2   = (bid & 31) * 32;
  const int l15  = lane & 15, l4 = lane >> 4;

  f32x4 acc = {0.f, 0.f, 0.f, 0.f};
  for (int kb = 0; kb < KK / BK; ++kb) {
    const int kbase = kb * BK;
#pragma unroll
    for (int i = 0; i < 2; ++i) {
      int c = tid + (i << 8);
      int r = c >> 4, kc = (c & 15) << 3;
      int m = m0 + r, k = kbase + kc;
      i32x4 v;
      if (k < NH) {
        v = *reinterpret_cast<const i32x4*>(rhb + (size_t)m * NH + k);
      } else {
        const float* xp = x + (size_t)m * (NT * ND) + (size_t)t * ND + (k - NH);
        f32x4 f0 = *reinterpret_cast<const f32x4*>(xp);
        f32x4 f1 = *reinterpret_cast<const f32x4*>(xp + 4);
        v[0] = pack2(f0[0], f0[1]); v[1] = pack2(f0[2], f0[3]);
        v[2] = pack2(f1[0], f1[1]); v[3] = pack2(f1[2], f1[3]);
      }
      int off = (r << 8) + (((kc << 1)) ^ ((r & 7) << 4));
      *reinterpret_cast<i32x4*>(&smem[off]) = v;
    }
#pragma unroll
    for (int i = 0; i < 2; ++i) {
      int c = tid + (i << 8);
      int n = c >> 4, kc = (c & 15) << 3;
      i32x4 v = *reinterpret_cast<const i32x4*>(B2t + (size_t)(n2 + n) * KK + kbase + kc);
      int off = 8192 + (n << 8) + (((kc << 1)) ^ ((n & 7) << 4));
      *reinterpret_cast<i32x4*>(&smem[off]) = v;
    }
    __syncthreads();
#pragma unroll
    for (int ks = 0; ks < 4; ++ks) {
      int kbyte = ks * 64 + l4 * 16;
      int ra = wm * 16 + l15;
      short8 a = *reinterpret_cast<short8*>(&smem[(ra << 8) + (kbyte ^ ((ra & 7) << 4))]);
      int nb = wn * 16 + l15;
      short8 b0 = *reinterpret_cast<short8*>(&smem[8192 + (nb << 8) + (kbyte ^ ((nb & 7) << 4))]);
      acc = __builtin_amdgcn_mfma_f32_16x16x32_bf16(a, b0, acc, 0, 0, 0);
    }
    __syncthreads();
  }
  int mrow = m0 + wm * 16 + l4 * 4;
  int c = n2 + wn * 16 + l15;
#pragma unroll
  for (int j = 0; j < 4; ++j) {
    int m = mrow + j;
    size_t idx = (size_t)m * NH + c;
    float hc = tanhf_(acc[j] + bb[c]);
    float zv = zfb[idx];
    float hn = (1.f - zv) * hf[idx] + zv * hc;
    hf[idx] = hn;
    hb[idx] = f2bf(hn);
    if (t == NT - 1) out[idx] = hn;
  }
}

// ===========================================================================
extern "C" void kernel_launch(void* const* d_in, const int* in_sizes, int n_in,
                              void* d_out, int out_size, void* d_ws, size_t ws_size,
                              hipStream_t stream) {
  const float* x  = (const float*)d_in[0];
  const float* W  = (const float*)d_in[1];
  const float* U  = (const float*)d_in[2];
  const float* Wz = (const float*)d_in[3];
  const float* Uz = (const float*)d_in[4];
  const float* Wr = (const float*)d_in[5];
  const float* Ur = (const float*)d_in[6];
  const float* bb = (const float*)d_in[7];
  const float* bz = (const float*)d_in[8];
  const float* br = (const float*)d_in[9];
  float* out = (float*)d_out;
  char* ws = (char*)d_ws;

  ushort_t* Bu1   = (ushort_t*)(ws);                  //  4,194,304
  ushort_t* Bu2   = (ushort_t*)(ws + 4194304);        //  2,097,152
  ushort_t* Bx    = (ushort_t*)(ws + 6291456);        //  3,145,728
  ushort_t* hb    = (ushort_t*)(ws + 9437184);        //    524,288
  ushort_t* rhb   = (ushort_t*)(ws + 9961472);        //    524,288
  float*    hf    = (float*)   (ws + 10485760);       //  1,048,576
  float*    zfb   = (float*)   (ws + 11534336);       //  1,048,576
  ushort_t* Gx    = (ushort_t*)(ws + 12587008);       // 805,306,368 -> 817,893,376

  const bool fast = (ws_size >= (size_t)817893376ULL);

  if (fast) {
    (void)hipFuncSetAttribute(reinterpret_cast<const void*>(&p1k5),
                              hipFuncAttributeMaxDynamicSharedMemorySize, 98304);
    hipLaunchKernelGGL(prep_all, dim3(16, 16, 7), dim3(256), 0, stream,
                       U, W, Uz, Wz, Ur, Wr, Bu1, Bu2, Bx, hb, hf);
    hipLaunchKernelGGL(gxgemm3, dim3(1024, 24), dim3(256), 0, stream,
                       x, Bx, bz, br, bb, Gx);
    for (int t = 0; t < NT; ++t) {
      hipLaunchKernelGGL(p1k5, dim3(256), dim3(512), 98304, stream,
                         Bu1, hb, rhb, hf, zfb, Gx, t);
      hipLaunchKernelGGL(p2k5, dim3(256), dim3(512), 0, stream,
                         Bu2, rhb, hb, hf, zfb, Gx, out, t);
    }
  } else {
    // fallback: proven round-2 per-step path (K=1536, biases in-loop)
    ushort_t* B1t  = (ushort_t*)(ws);
    ushort_t* B2t  = (ushort_t*)(ws + 6291456);
    ushort_t* hb2  = (ushort_t*)(ws + 9437184);
    ushort_t* rhb2 = (ushort_t*)(ws + 9961472);
    float*    hf2  = (float*)   (ws + 10485760);
    float*    zfb2 = (float*)   (ws + 11534336);
    hipLaunchKernelGGL(repack_weights, dim3(24, 32, 2), dim3(256), 0, stream,
                       U, W, Uz, Wz, Ur, Wr, B1t, B2t);
    hipLaunchKernelGGL(init_state, dim3(1024), dim3(256), 0, stream, hb2, hf2);
    for (int t = 0; t < NT; ++t) {
      hipLaunchKernelGGL(gru_phase1, dim3(256), dim3(256), 0, stream,
                         x, B1t, hb2, rhb2, hf2, zfb2, bz, br, t);
      hipLaunchKernelGGL(gru_phase2, dim3(256), dim3(256), 0, stream,
                         x, B2t, hb2, rhb2, hf2, zfb2, bb, out, t);
    }
  }
}